// Round 5
// baseline (264.708 us; speedup 1.0000x reference)
//
#include <hip/hip_runtime.h>
#include <math.h>

#define N_NODES 4096
#define H 64
#define NE 24576
#define KNN 15

__device__ __forceinline__ int mbcnt64(unsigned long long m) {
    int lo = __builtin_amdgcn_mbcnt_lo((unsigned int)m, 0u);
    return __builtin_amdgcn_mbcnt_hi((unsigned int)(m >> 32), lo);
}

// ---------------- zero out + deg counters, build xp = (x,y,z,|x|^2) ----------------
__global__ __launch_bounds__(256) void k_zero_init(float* __restrict__ out, int* __restrict__ degR,
                                                   int* __restrict__ degC, const float* __restrict__ x,
                                                   float4* __restrict__ xp) {
    int tid = blockIdx.x * 256 + threadIdx.x;
    if (tid < N_NODES) {
        degR[tid] = 0; degC[tid] = 0;
        float a = x[tid * 3], b = x[tid * 3 + 1], c = x[tid * 3 + 2];
        xp[tid] = make_float4(a, b, c, a * a + b * b + c * c);
    }
    float4 z = {0.f, 0.f, 0.f, 0.f};
    float4* o = (float4*)out;
    const int n4 = (N_NODES * N_NODES) / 4;
    int stride = gridDim.x * 256;
    for (int j = tid; j < n4; j += stride) o[j] = z;
}

// ---------------- histogram of original edges ----------------
__global__ void k_hist(const int* __restrict__ edges, int* degR, int* degC) {
    int e = blockIdx.x * blockDim.x + threadIdx.x;
    if (e < NE) {
        atomicAdd(&degR[edges[e]], 1);
        atomicAdd(&degC[edges[NE + e]], 1);
    }
}

// ---------------- barrier-free scan: wave0 -> rowptr/cursR, wave1 -> colptr/cursC ----------------
__global__ __launch_bounds__(128) void k_scan2(const int* __restrict__ degR, const int* __restrict__ degC,
                                               int* rowptr, int* colptr, int* cursR, int* cursC) {
    int w = threadIdx.x >> 6, lane = threadIdx.x & 63;
    const int* deg = w ? degC : degR;
    int* ptr  = w ? colptr : rowptr;
    int* curs = w ? cursC : cursR;
    const int4* d4 = (const int4*)deg + lane * 16;
    int4 v[16];
    int s = 0;
#pragma unroll
    for (int t = 0; t < 16; ++t) { v[t] = d4[t]; s += v[t].x + v[t].y + v[t].z + v[t].w; }
    int incl = s;
#pragma unroll
    for (int o = 1; o < 64; o <<= 1) { int u = __shfl_up(incl, o); if (lane >= o) incl += u; }
    int run = incl - s;
    int4* p4 = (int4*)ptr + lane * 16;
    int4* c4 = (int4*)curs + lane * 16;
#pragma unroll
    for (int t = 0; t < 16; ++t) {
        int4 o;
        o.x = run; run += v[t].x;
        o.y = run; run += v[t].y;
        o.z = run; run += v[t].z;
        o.w = run; run += v[t].w;
        p4[t] = o; c4[t] = o;
    }
    if (lane == 63) ptr[N_NODES] = run;
}

// ---------------- scatter edge ids into CSR (by r) and CSC (by c) ----------------
__global__ void k_scatter(const int* __restrict__ edges, int* cursR, int* cursC, int* eidR, int* eidC) {
    int e = blockIdx.x * blockDim.x + threadIdx.x;
    if (e < NE) {
        int r = edges[e], c = edges[NE + e];
        int p = atomicAdd(&cursR[r], 1); eidR[p] = e;
        int q = atomicAdd(&cursC[c], 1); eidC[q] = e;
    }
}

// ---------------- kNN: block per node, 4 waves x 1024 candidates, fixed-tau ballot filter ----------------
__global__ __launch_bounds__(256) void k_knn(const float4* __restrict__ xp, int* __restrict__ knn_idx) {
    __shared__ float cd[4][256];
    __shared__ int   ci[4][256];
    __shared__ float md[64];
    __shared__ int   mi[64];
    const int w = threadIdx.x >> 6;
    const int lane = threadIdx.x & 63;
    const int i = blockIdx.x;
    const float4 pi = xp[i];
    const int jbase = w * 1024;
    float tau;
    int cnt;

    // select top-KNN of cd/ci[w][0..cnt) -> cd/ci[w][0..KNN), set tau = KNN-th dist, cnt = KNN
    auto compact = [&]() {
        __builtin_amdgcn_wave_barrier();
        float v[4]; int s_in[4];
#pragma unroll
        for (int t = 0; t < 4; ++t) {
            int s = lane + 64 * t;
            v[t] = (s < cnt) ? cd[w][s] : INFINITY;
        }
        float wd = INFINITY; int wi = 0;
        float lastbd = INFINITY;
        for (int r = 0; r < KNN; ++r) {
            float bd = v[0]; int bt = 0;
#pragma unroll
            for (int t = 1; t < 4; ++t) { if (v[t] < bd) { bd = v[t]; bt = t; } }
            int bs = lane + 64 * bt;
#pragma unroll
            for (int o = 32; o > 0; o >>= 1) {
                float od = __shfl_xor(bd, o);
                int   os = __shfl_xor(bs, o);
                if (od < bd || (od == bd && os < bs)) { bd = od; bs = os; }
            }
            int widx = ci[w][bs];             // bs wave-uniform -> broadcast read
            if (lane == r) { wd = bd; wi = widx; }
            int own = bs & 63, bt2 = bs >> 6;
            if (lane == own) {
#pragma unroll
                for (int t = 0; t < 4; ++t) { if (t == bt2) v[t] = INFINITY; }
            }
            lastbd = bd;
        }
        __builtin_amdgcn_wave_barrier();
        if (lane < KNN) { cd[w][lane] = wd; ci[w][lane] = wi; }
        cnt = KNN;
        tau = lastbd;
        __builtin_amdgcn_wave_barrier();
        (void)s_in;
    };

    // iteration 0: no filter, establish tau
    {
        int j = jbase + lane;
        float4 pj = xp[j];
        float d = pi.w + pj.w - 2.0f * (pi.x * pj.x + pi.y * pj.y + pi.z * pj.z);
        bool pred = (j != i);
        unsigned long long mask = __ballot(pred);
        int before = mbcnt64(mask);
        if (pred) { cd[w][before] = d; ci[w][before] = j; }
        cnt = __popcll(mask);
        compact();
    }

    // iterations 1..15: lean filtered append
    for (int iter = 1; iter < 16; ++iter) {
        int j = jbase + iter * 64 + lane;
        float4 pj = xp[j];
        float d = pi.w + pj.w - 2.0f * (pi.x * pj.x + pi.y * pj.y + pi.z * pj.z);
        bool pred = (d < tau) && (j != i);
        unsigned long long mask = __ballot(pred);
        int before = mbcnt64(mask);
        if (pred) { cd[w][cnt + before] = d; ci[w][cnt + before] = j; }
        cnt += __popcll(mask);
        if (cnt > 192) compact();   // statistically never fires; guarantees no overflow
    }
    compact();                      // local top-15 in cd/ci[w][0..15)

    if (lane < KNN) { md[w * 16 + lane] = cd[w][lane]; mi[w * 16 + lane] = ci[w][lane]; }
    __syncthreads();

    // wave 0 merges 4x15 -> 15
    if (w == 0) {
        float v = ((lane & 15) < KNN) ? md[lane] : INFINITY;
        int  vi = ((lane & 15) < KNN) ? mi[lane] : 0;
        float wd = INFINITY; int wi = 0;
        for (int r = 0; r < KNN; ++r) {
            float bd = v; int bs = lane;
#pragma unroll
            for (int o = 32; o > 0; o >>= 1) {
                float od = __shfl_xor(bd, o);
                int   os = __shfl_xor(bs, o);
                if (od < bd || (od == bd && os < bs)) { bd = od; bs = os; }
            }
            int widx = __shfl(vi, bs);
            if (lane == r) { wd = bd; wi = widx; }
            if (lane == bs) v = INFINITY;
        }
        if (lane < KNN) knn_idx[i * KNN + lane] = wi;
        (void)wd;
    }
}

// ---------------- DevConv max-agg + Wp/Wq/Wk (fused, block = 1 wave per node) ----------------
__global__ __launch_bounds__(64) void k_agg_feat_qk(const float4* __restrict__ xp, const int* __restrict__ edges,
                                                    const int* __restrict__ rowptr, const int* __restrict__ eidR,
                                                    const int* __restrict__ knn_idx, const float* __restrict__ Wt,
                                                    const float* __restrict__ Wp, const float* __restrict__ Wq,
                                                    const float* __restrict__ Wk,
                                                    float* __restrict__ qb, float* __restrict__ kb) {
    int i = blockIdx.x, h = threadIdx.x;
    __shared__ float mrow[H], frow[H];
    float w0 = Wt[h * 3], w1 = Wt[h * 3 + 1], w2 = Wt[h * 3 + 2];
    float4 pi = xp[i];
    float m = -INFINITY;
    int s0 = rowptr[i], s1 = rowptr[i + 1];
    for (int s = s0; s < s1; ++s) {
        int e = eidR[s];
        float4 pj = xp[edges[NE + e]];
        m = fmaxf(m, w0 * (pj.x - pi.x) + w1 * (pj.y - pi.y) + w2 * (pj.z - pi.z));
    }
    for (int t = 0; t < KNN; ++t) {
        float4 pj = xp[knn_idx[i * KNN + t]];
        m = fmaxf(m, w0 * (pj.x - pi.x) + w1 * (pj.y - pi.y) + w2 * (pj.z - pi.z));
    }
    if (!(m > -INFINITY)) m = 0.0f;
    mrow[h] = m;
    __syncthreads();
    float f = 0.f;
    for (int k2 = 0; k2 < H; ++k2) f += Wp[h * H + k2] * mrow[k2];
    frow[h] = f;
    __syncthreads();
    float qv = 0.f, kv = 0.f;
    for (int k2 = 0; k2 < H; ++k2) {
        float fr = frow[k2];
        qv += Wq[h * H + k2] * fr;
        kv += Wk[h * H + k2] * fr;
    }
    qb[i * H + h] = qv;
    kb[i * H + h] = kv;
}

// ---------------- attention scores: 1 wave per original edge ----------------
__global__ __launch_bounds__(256) void k_att(const int* __restrict__ edges, const float* __restrict__ qb,
                                             const float* __restrict__ kb, float* __restrict__ att) {
    int wid = (blockIdx.x * blockDim.x + threadIdx.x) >> 6;
    int lane = threadIdx.x & 63;
    if (wid >= NE) return;
    int r = edges[wid], c = edges[NE + wid];
    float v = qb[r * H + lane] * kb[c * H + lane];
#pragma unroll
    for (int o = 32; o > 0; o >>= 1) v += __shfl_xor(v, o);
    if (lane == 0) att[wid] = v;
}

// ---------------- segment softmax: 1 thread per node ----------------
__global__ void k_softmax(const int* __restrict__ rowptr, const int* __restrict__ eidR,
                          const float* __restrict__ att, float* __restrict__ attn) {
    int i = blockIdx.x * blockDim.x + threadIdx.x;
    if (i >= N_NODES) return;
    int s0 = rowptr[i], s1 = rowptr[i + 1];
    float m = -INFINITY;
    for (int s = s0; s < s1; ++s) m = fmaxf(m, att[eidR[s]]);
    float den = 0.f;
    for (int s = s0; s < s1; ++s) den += expf(att[eidR[s]] - m);
    for (int s = s0; s < s1; ++s) { int e = eidR[s]; attn[e] = expf(att[e] - m) / den; }
}

// ---------------- final scatter: thread = (S-edge e1, fan-slot s), s strides A-row(c) ----------------
__global__ __launch_bounds__(256) void k_pair2(const int* __restrict__ edges,
                                               const int* __restrict__ rowptr, const int* __restrict__ eidR,
                                               const int* __restrict__ colptr, const int* __restrict__ eidC,
                                               const float* __restrict__ attn, float* __restrict__ out) {
    int tid = blockIdx.x * 256 + threadIdx.x;
    int e1 = tid >> 5, s = tid & 31;
    if (e1 >= NE) return;
    int c = edges[NE + e1];
    int a0 = rowptr[c], a1 = rowptr[c + 1];
    if (a0 + s >= a1) return;
    int r = edges[e1];
    float sv = attn[e1];
    float* orow = out + (size_t)r * N_NODES;
    for (int a = a0 + s; a < a1; a += 32) {
        int e2 = eidR[a];
        int c2 = edges[NE + e2];
        int b0 = colptr[c2], b1 = colptr[c2 + 1];
        for (int b = b0; b < b1; ++b) {
            int e3 = eidC[b];
            int j = edges[e3];
            atomicAdd(&orow[j], sv * attn[e3]);
        }
    }
}

extern "C" void kernel_launch(void* const* d_in, const int* in_sizes, int n_in,
                              void* d_out, int out_size, void* d_ws, size_t ws_size,
                              hipStream_t stream) {
    const float* x    = (const float*)d_in[0];
    const int* edges  = (const int*)d_in[1];
    const float* Wt   = (const float*)d_in[2];
    const float* Wp   = (const float*)d_in[3];
    const float* Wq   = (const float*)d_in[4];
    const float* Wk   = (const float*)d_in[5];
    float* out = (float*)d_out;

    char* w = (char*)d_ws;
    size_t off = 0;
    auto alloc = [&](size_t bytes) -> void* {
        void* p = w + off;
        off += (bytes + 255) & ~(size_t)255;
        return p;
    };
    float4* xp    = (float4*)alloc((size_t)N_NODES * 16);
    int*   knn    = (int*)  alloc((size_t)N_NODES * KNN * 4);
    float* qb     = (float*)alloc((size_t)N_NODES * H * 4);
    float* kb     = (float*)alloc((size_t)N_NODES * H * 4);
    float* att    = (float*)alloc((size_t)NE * 4);
    float* attn   = (float*)alloc((size_t)NE * 4);
    int*   degR   = (int*)  alloc((size_t)N_NODES * 4);
    int*   degC   = (int*)  alloc((size_t)N_NODES * 4);
    int*   rowptr = (int*)  alloc((size_t)(N_NODES + 4) * 4);
    int*   colptr = (int*)  alloc((size_t)(N_NODES + 4) * 4);
    int*   cursR  = (int*)  alloc((size_t)N_NODES * 4);
    int*   cursC  = (int*)  alloc((size_t)N_NODES * 4);
    int*   eidR   = (int*)  alloc((size_t)NE * 4);
    int*   eidC   = (int*)  alloc((size_t)NE * 4);

    k_zero_init<<<2048, 256, 0, stream>>>(out, degR, degC, x, xp);
    k_hist<<<(NE + 255) / 256, 256, 0, stream>>>(edges, degR, degC);
    k_knn<<<N_NODES, 256, 0, stream>>>(xp, knn);
    k_scan2<<<1, 128, 0, stream>>>(degR, degC, rowptr, colptr, cursR, cursC);
    k_scatter<<<(NE + 255) / 256, 256, 0, stream>>>(edges, cursR, cursC, eidR, eidC);
    k_agg_feat_qk<<<N_NODES, 64, 0, stream>>>(xp, edges, rowptr, eidR, knn, Wt, Wp, Wq, Wk, qb, kb);
    k_att<<<(NE * 64) / 256, 256, 0, stream>>>(edges, qb, kb, att);
    k_softmax<<<(N_NODES + 255) / 256, 256, 0, stream>>>(rowptr, eidR, att, attn);
    k_pair2<<<(NE * 32) / 256, 256, 0, stream>>>(edges, rowptr, eidR, colptr, eidC, attn, out);
}

// Round 6
// 186.685 us; speedup vs baseline: 1.4179x; 1.4179x over previous
//
#include <hip/hip_runtime.h>
#include <math.h>

#define N_NODES 4096
#define H 64
#define NE 24576
#define KNN 15
#define KBUF 448

__device__ __forceinline__ int mbcnt64(unsigned long long m) {
    int lo = __builtin_amdgcn_mbcnt_lo((unsigned int)m, 0u);
    return __builtin_amdgcn_mbcnt_hi((unsigned int)(m >> 32), lo);
}

// ---------------- zero out + deg counters, build xp = (x,y,z,|x|^2) ----------------
__global__ __launch_bounds__(256) void k_zero_init(float* __restrict__ out, int* __restrict__ degR,
                                                   int* __restrict__ degC, const float* __restrict__ x,
                                                   float4* __restrict__ xp) {
    int tid = blockIdx.x * 256 + threadIdx.x;
    if (tid < N_NODES) {
        degR[tid] = 0; degC[tid] = 0;
        float a = x[tid * 3], b = x[tid * 3 + 1], c = x[tid * 3 + 2];
        xp[tid] = make_float4(a, b, c, a * a + b * b + c * c);
    }
    float4 z = {0.f, 0.f, 0.f, 0.f};
    float4* o = (float4*)out;
    const int n4 = (N_NODES * N_NODES) / 4;
    int stride = gridDim.x * 256;
    for (int j = tid; j < n4; j += stride) o[j] = z;
}

// ---------------- histogram of original edges ----------------
__global__ void k_hist(const int* __restrict__ edges, int* degR, int* degC) {
    int e = blockIdx.x * blockDim.x + threadIdx.x;
    if (e < NE) {
        atomicAdd(&degR[edges[e]], 1);
        atomicAdd(&degC[edges[NE + e]], 1);
    }
}

// ---------------- barrier-free scan: wave0 -> rowptr/cursR, wave1 -> colptr/cursC ----------------
__global__ __launch_bounds__(128) void k_scan2(const int* __restrict__ degR, const int* __restrict__ degC,
                                               int* rowptr, int* colptr, int* cursR, int* cursC) {
    int w = threadIdx.x >> 6, lane = threadIdx.x & 63;
    const int* deg = w ? degC : degR;
    int* ptr  = w ? colptr : rowptr;
    int* curs = w ? cursC : cursR;
    const int4* d4 = (const int4*)deg + lane * 16;
    int4 v[16];
    int s = 0;
#pragma unroll
    for (int t = 0; t < 16; ++t) { v[t] = d4[t]; s += v[t].x + v[t].y + v[t].z + v[t].w; }
    int incl = s;
#pragma unroll
    for (int o = 1; o < 64; o <<= 1) { int u = __shfl_up(incl, o); if (lane >= o) incl += u; }
    int run = incl - s;
    int4* p4 = (int4*)ptr + lane * 16;
    int4* c4 = (int4*)curs + lane * 16;
#pragma unroll
    for (int t = 0; t < 16; ++t) {
        int4 o;
        o.x = run; run += v[t].x;
        o.y = run; run += v[t].y;
        o.z = run; run += v[t].z;
        o.w = run; run += v[t].w;
        p4[t] = o; c4[t] = o;
    }
    if (lane == 63) ptr[N_NODES] = run;
}

// ---------------- scatter edge ids into CSR (by r) and CSC (by c) ----------------
__global__ void k_scatter(const int* __restrict__ edges, int* cursR, int* cursC, int* eidR, int* eidC) {
    int e = blockIdx.x * blockDim.x + threadIdx.x;
    if (e < NE) {
        int r = edges[e], c = edges[NE + e];
        int p = atomicAdd(&cursR[r], 1); eidR[p] = e;
        int q = atomicAdd(&cursC[c], 1); eidC[q] = e;
    }
}

// ---------------- kNN: wave per node, 4 candidates/lane/iter, ballot-append + rare compact ----------------
__global__ __launch_bounds__(256) void k_knn(const float4* __restrict__ xp, int* __restrict__ knn_idx) {
    __shared__ float cd[4][KBUF];
    __shared__ int   ci[4][KBUF];
    const int w = threadIdx.x >> 6;
    const int lane = threadIdx.x & 63;
    const int i = blockIdx.x * 4 + w;
    const float4 pi = xp[i];
    float tau = INFINITY;
    int cnt = 0;
    float wd = INFINITY; int wi = 0;   // lane r (<15) holds r-th winner after compact

    // exact top-KNN of cd/ci[w][0..cnt) -> winners in wd/wi + re-stored at slots 0..14; tau = 15th
    auto compact = [&]() {
        __builtin_amdgcn_wave_barrier();
        float v[7];
#pragma unroll
        for (int t = 0; t < 7; ++t) {
            int s = lane + 64 * t;
            v[t] = (s < cnt) ? cd[w][s] : INFINITY;
        }
        float lastbd = INFINITY;
        for (int r = 0; r < KNN; ++r) {
            float bd = v[0]; int bt = 0;
#pragma unroll
            for (int t = 1; t < 7; ++t) { if (v[t] < bd) { bd = v[t]; bt = t; } }
            int bs = bt * 64 + lane;
#pragma unroll
            for (int o = 32; o > 0; o >>= 1) {
                float od = __shfl_xor(bd, o);
                int   os = __shfl_xor(bs, o);
                if (od < bd || (od == bd && os < bs)) { bd = od; bs = os; }
            }
            int widx = ci[w][bs];             // bs wave-uniform -> broadcast read
            if (lane == r) { wd = bd; wi = widx; }
            if (lane == (bs & 63)) {
                int bt2 = bs >> 6;
#pragma unroll
                for (int t = 0; t < 7; ++t) { if (t == bt2) v[t] = INFINITY; }
            }
            lastbd = bd;
        }
        __builtin_amdgcn_wave_barrier();
        if (lane < KNN) { cd[w][lane] = wd; ci[w][lane] = wi; }
        cnt = KNN;
        tau = lastbd;
        __builtin_amdgcn_wave_barrier();
    };

    for (int iter = 0; iter < 16; ++iter) {
        const int jb = iter * 256;
        // 4 independent candidates per lane; slot order (t, lane) == index order
        float4 p0 = xp[jb + lane];
        float4 p1 = xp[jb + 64 + lane];
        float4 p2 = xp[jb + 128 + lane];
        float4 p3 = xp[jb + 192 + lane];
        float d0 = pi.w + p0.w - 2.0f * (pi.x * p0.x + pi.y * p0.y + pi.z * p0.z);
        float d1 = pi.w + p1.w - 2.0f * (pi.x * p1.x + pi.y * p1.y + pi.z * p1.z);
        float d2 = pi.w + p2.w - 2.0f * (pi.x * p2.x + pi.y * p2.y + pi.z * p2.z);
        float d3 = pi.w + p3.w - 2.0f * (pi.x * p3.x + pi.y * p3.y + pi.z * p3.z);
#pragma unroll
        for (int t = 0; t < 4; ++t) {
            float d = (t == 0) ? d0 : (t == 1) ? d1 : (t == 2) ? d2 : d3;
            int j = jb + t * 64 + lane;
            bool pred = (d < tau) && (j != i);
            unsigned long long m = __ballot(pred);
            if (pred) { int s = cnt + mbcnt64(m); cd[w][s] = d; ci[w][s] = j; }
            cnt += __popcll(m);
        }
        if (cnt > KBUF - 256) compact();   // fires at iter 0 (establishes tau); rare afterwards
    }
    compact();
    if (lane < KNN) knn_idx[i * KNN + lane] = wi;
}

// ---------------- DevConv max-agg + Wp/Wq/Wk (fused, block = 1 wave per node) ----------------
__global__ __launch_bounds__(64) void k_agg_feat_qk(const float4* __restrict__ xp, const int* __restrict__ edges,
                                                    const int* __restrict__ rowptr, const int* __restrict__ eidR,
                                                    const int* __restrict__ knn_idx, const float* __restrict__ Wt,
                                                    const float* __restrict__ Wp, const float* __restrict__ Wq,
                                                    const float* __restrict__ Wk,
                                                    float* __restrict__ qb, float* __restrict__ kb) {
    int i = blockIdx.x, h = threadIdx.x;
    __shared__ float mrow[H], frow[H];
    float w0 = Wt[h * 3], w1 = Wt[h * 3 + 1], w2 = Wt[h * 3 + 2];
    float4 pi = xp[i];
    float m = -INFINITY;
    int s0 = rowptr[i], s1 = rowptr[i + 1];
    for (int s = s0; s < s1; ++s) {
        int e = eidR[s];
        float4 pj = xp[edges[NE + e]];
        m = fmaxf(m, w0 * (pj.x - pi.x) + w1 * (pj.y - pi.y) + w2 * (pj.z - pi.z));
    }
    for (int t = 0; t < KNN; ++t) {
        float4 pj = xp[knn_idx[i * KNN + t]];
        m = fmaxf(m, w0 * (pj.x - pi.x) + w1 * (pj.y - pi.y) + w2 * (pj.z - pi.z));
    }
    if (!(m > -INFINITY)) m = 0.0f;
    mrow[h] = m;
    __syncthreads();
    float f = 0.f;
    for (int k2 = 0; k2 < H; ++k2) f += Wp[h * H + k2] * mrow[k2];
    frow[h] = f;
    __syncthreads();
    float qv = 0.f, kv = 0.f;
    for (int k2 = 0; k2 < H; ++k2) {
        float fr = frow[k2];
        qv += Wq[h * H + k2] * fr;
        kv += Wk[h * H + k2] * fr;
    }
    qb[i * H + h] = qv;
    kb[i * H + h] = kv;
}

// ---------------- attention scores: 1 wave per original edge ----------------
__global__ __launch_bounds__(256) void k_att(const int* __restrict__ edges, const float* __restrict__ qb,
                                             const float* __restrict__ kb, float* __restrict__ att) {
    int wid = (blockIdx.x * blockDim.x + threadIdx.x) >> 6;
    int lane = threadIdx.x & 63;
    if (wid >= NE) return;
    int r = edges[wid], c = edges[NE + wid];
    float v = qb[r * H + lane] * kb[c * H + lane];
#pragma unroll
    for (int o = 32; o > 0; o >>= 1) v += __shfl_xor(v, o);
    if (lane == 0) att[wid] = v;
}

// ---------------- segment softmax: 1 thread per node ----------------
__global__ void k_softmax(const int* __restrict__ rowptr, const int* __restrict__ eidR,
                          const float* __restrict__ att, float* __restrict__ attn) {
    int i = blockIdx.x * blockDim.x + threadIdx.x;
    if (i >= N_NODES) return;
    int s0 = rowptr[i], s1 = rowptr[i + 1];
    float m = -INFINITY;
    for (int s = s0; s < s1; ++s) m = fmaxf(m, att[eidR[s]]);
    float den = 0.f;
    for (int s = s0; s < s1; ++s) den += expf(att[eidR[s]] - m);
    for (int s = s0; s < s1; ++s) { int e = eidR[s]; attn[e] = expf(att[e] - m) / den; }
}

// ---------------- final scatter: thread = (S-edge e1, fan-slot s), s strides A-row(c) ----------------
__global__ __launch_bounds__(256) void k_pair2(const int* __restrict__ edges,
                                               const int* __restrict__ rowptr, const int* __restrict__ eidR,
                                               const int* __restrict__ colptr, const int* __restrict__ eidC,
                                               const float* __restrict__ attn, float* __restrict__ out) {
    int tid = blockIdx.x * 256 + threadIdx.x;
    int e1 = tid >> 5, s = tid & 31;
    if (e1 >= NE) return;
    int c = edges[NE + e1];
    int a0 = rowptr[c], a1 = rowptr[c + 1];
    if (a0 + s >= a1) return;
    int r = edges[e1];
    float sv = attn[e1];
    float* orow = out + (size_t)r * N_NODES;
    for (int a = a0 + s; a < a1; a += 32) {
        int e2 = eidR[a];
        int c2 = edges[NE + e2];
        int b0 = colptr[c2], b1 = colptr[c2 + 1];
        for (int b = b0; b < b1; ++b) {
            int e3 = eidC[b];
            int j = edges[e3];
            atomicAdd(&orow[j], sv * attn[e3]);
        }
    }
}

extern "C" void kernel_launch(void* const* d_in, const int* in_sizes, int n_in,
                              void* d_out, int out_size, void* d_ws, size_t ws_size,
                              hipStream_t stream) {
    const float* x    = (const float*)d_in[0];
    const int* edges  = (const int*)d_in[1];
    const float* Wt   = (const float*)d_in[2];
    const float* Wp   = (const float*)d_in[3];
    const float* Wq   = (const float*)d_in[4];
    const float* Wk   = (const float*)d_in[5];
    float* out = (float*)d_out;

    char* w = (char*)d_ws;
    size_t off = 0;
    auto alloc = [&](size_t bytes) -> void* {
        void* p = w + off;
        off += (bytes + 255) & ~(size_t)255;
        return p;
    };
    float4* xp    = (float4*)alloc((size_t)N_NODES * 16);
    int*   knn    = (int*)  alloc((size_t)N_NODES * KNN * 4);
    float* qb     = (float*)alloc((size_t)N_NODES * H * 4);
    float* kb     = (float*)alloc((size_t)N_NODES * H * 4);
    float* att    = (float*)alloc((size_t)NE * 4);
    float* attn   = (float*)alloc((size_t)NE * 4);
    int*   degR   = (int*)  alloc((size_t)N_NODES * 4);
    int*   degC   = (int*)  alloc((size_t)N_NODES * 4);
    int*   rowptr = (int*)  alloc((size_t)(N_NODES + 4) * 4);
    int*   colptr = (int*)  alloc((size_t)(N_NODES + 4) * 4);
    int*   cursR  = (int*)  alloc((size_t)N_NODES * 4);
    int*   cursC  = (int*)  alloc((size_t)N_NODES * 4);
    int*   eidR   = (int*)  alloc((size_t)NE * 4);
    int*   eidC   = (int*)  alloc((size_t)NE * 4);

    k_zero_init<<<2048, 256, 0, stream>>>(out, degR, degC, x, xp);
    k_hist<<<(NE + 255) / 256, 256, 0, stream>>>(edges, degR, degC);
    k_knn<<<N_NODES / 4, 256, 0, stream>>>(xp, knn);
    k_scan2<<<1, 128, 0, stream>>>(degR, degC, rowptr, colptr, cursR, cursC);
    k_scatter<<<(NE + 255) / 256, 256, 0, stream>>>(edges, cursR, cursC, eidR, eidC);
    k_agg_feat_qk<<<N_NODES, 64, 0, stream>>>(xp, edges, rowptr, eidR, knn, Wt, Wp, Wq, Wk, qb, kb);
    k_att<<<(NE * 64) / 256, 256, 0, stream>>>(edges, qb, kb, att);
    k_softmax<<<(N_NODES + 255) / 256, 256, 0, stream>>>(rowptr, eidR, att, attn);
    k_pair2<<<(NE * 32) / 256, 256, 0, stream>>>(edges, rowptr, eidR, colptr, eidC, attn, out);
}

// Round 7
// 151.063 us; speedup vs baseline: 1.7523x; 1.2358x over previous
//
#include <hip/hip_runtime.h>
#include <math.h>

#define N_NODES 4096
#define H 64
#define NE 24576
#define KNN 15
#define KBUF 448
#define MAXPAIRS 393216

__device__ __forceinline__ int mbcnt64(unsigned long long m) {
    int lo = __builtin_amdgcn_mbcnt_lo((unsigned int)m, 0u);
    return __builtin_amdgcn_mbcnt_hi((unsigned int)(m >> 32), lo);
}

// ---------------- init: deg counters + xp = (x,y,z,|x|^2) ----------------
__global__ __launch_bounds__(256) void k_init2(int* __restrict__ degR, int* __restrict__ degC,
                                               const float* __restrict__ x, float4* __restrict__ xp) {
    int tid = blockIdx.x * 256 + threadIdx.x;
    if (tid < N_NODES) {
        degR[tid] = 0; degC[tid] = 0;
        float a = x[tid * 3], b = x[tid * 3 + 1], c = x[tid * 3 + 2];
        xp[tid] = make_float4(a, b, c, a * a + b * b + c * c);
    }
}

// ---------------- histogram of original edges ----------------
__global__ void k_hist(const int* __restrict__ edges, int* degR, int* degC) {
    int e = blockIdx.x * blockDim.x + threadIdx.x;
    if (e < NE) {
        atomicAdd(&degR[edges[e]], 1);
        atomicAdd(&degC[edges[NE + e]], 1);
    }
}

// ---------------- barrier-free scan: wave0 -> rowptr/cursR, wave1 -> colptr/cursC ----------------
__global__ __launch_bounds__(128) void k_scan2(const int* __restrict__ degR, const int* __restrict__ degC,
                                               int* rowptr, int* colptr, int* cursR, int* cursC) {
    int w = threadIdx.x >> 6, lane = threadIdx.x & 63;
    const int* deg = w ? degC : degR;
    int* ptr  = w ? colptr : rowptr;
    int* curs = w ? cursC : cursR;
    const int4* d4 = (const int4*)deg + lane * 16;
    int4 v[16];
    int s = 0;
#pragma unroll
    for (int t = 0; t < 16; ++t) { v[t] = d4[t]; s += v[t].x + v[t].y + v[t].z + v[t].w; }
    int incl = s;
#pragma unroll
    for (int o = 1; o < 64; o <<= 1) { int u = __shfl_up(incl, o); if (lane >= o) incl += u; }
    int run = incl - s;
    int4* p4 = (int4*)ptr + lane * 16;
    int4* c4 = (int4*)curs + lane * 16;
#pragma unroll
    for (int t = 0; t < 16; ++t) {
        int4 o;
        o.x = run; run += v[t].x;
        o.y = run; run += v[t].y;
        o.z = run; run += v[t].z;
        o.w = run; run += v[t].w;
        p4[t] = o; c4[t] = o;
    }
    if (lane == 63) ptr[N_NODES] = run;
}

// ---------------- scatter edge ids into CSR/CSC; pair-count per CSR slot ----------------
__global__ void k_scatter(const int* __restrict__ edges, const int* __restrict__ rowptr,
                          int* cursR, int* cursC, int* eidR, int* eidC, int* pcnt2) {
    int e = blockIdx.x * blockDim.x + threadIdx.x;
    if (e < NE) {
        int r = edges[e], c = edges[NE + e];
        int p = atomicAdd(&cursR[r], 1); eidR[p] = e;
        int q = atomicAdd(&cursC[c], 1); eidC[q] = e;
        pcnt2[p] = rowptr[c + 1] - rowptr[c];   // pairs spawned by this CSR slot
    }
}

// ---------------- scan of pair counts over CSR slots (one block, 1024 x 24) ----------------
__global__ __launch_bounds__(1024) void k_pscan(const int* __restrict__ pcnt2, int* __restrict__ poff) {
    __shared__ int buf[1024];
    int t = threadIdx.x;
    int v[24];
    int s = 0;
    int base = t * 24;
#pragma unroll
    for (int k2 = 0; k2 < 24; ++k2) { v[k2] = pcnt2[base + k2]; s += v[k2]; }
    buf[t] = s;
    __syncthreads();
    int acc = s;
    for (int o = 1; o < 1024; o <<= 1) {
        int other = (t >= o) ? buf[t - o] : 0;
        __syncthreads();
        acc += other;
        buf[t] = acc;
        __syncthreads();
    }
    int run = acc - s;  // exclusive
#pragma unroll
    for (int k2 = 0; k2 < 24; ++k2) { poff[base + k2] = run; run += v[k2]; }
    if (t == 1023) poff[NE] = run;
}

// ---------------- kNN: wave per node, 4 candidates/lane/iter, ballot-append + rare compact ----------------
__global__ __launch_bounds__(256) void k_knn(const float4* __restrict__ xp, int* __restrict__ knn_idx) {
    __shared__ float cd[4][KBUF];
    __shared__ int   ci[4][KBUF];
    const int w = threadIdx.x >> 6;
    const int lane = threadIdx.x & 63;
    const int i = blockIdx.x * 4 + w;
    const float4 pi = xp[i];
    float tau = INFINITY;
    int cnt = 0;
    float wd = INFINITY; int wi = 0;   // lane r (<15) holds r-th winner after compact

    auto compact = [&]() {
        __builtin_amdgcn_wave_barrier();
        float v[7];
#pragma unroll
        for (int t = 0; t < 7; ++t) {
            int s = lane + 64 * t;
            v[t] = (s < cnt) ? cd[w][s] : INFINITY;
        }
        float lastbd = INFINITY;
        for (int r = 0; r < KNN; ++r) {
            float bd = v[0]; int bt = 0;
#pragma unroll
            for (int t = 1; t < 7; ++t) { if (v[t] < bd) { bd = v[t]; bt = t; } }
            int bs = bt * 64 + lane;
#pragma unroll
            for (int o = 32; o > 0; o >>= 1) {
                float od = __shfl_xor(bd, o);
                int   os = __shfl_xor(bs, o);
                if (od < bd || (od == bd && os < bs)) { bd = od; bs = os; }
            }
            int widx = ci[w][bs];             // bs wave-uniform -> broadcast read
            if (lane == r) { wd = bd; wi = widx; }
            if (lane == (bs & 63)) {
                int bt2 = bs >> 6;
#pragma unroll
                for (int t = 0; t < 7; ++t) { if (t == bt2) v[t] = INFINITY; }
            }
            lastbd = bd;
        }
        __builtin_amdgcn_wave_barrier();
        if (lane < KNN) { cd[w][lane] = wd; ci[w][lane] = wi; }
        cnt = KNN;
        tau = lastbd;
        __builtin_amdgcn_wave_barrier();
    };

    for (int iter = 0; iter < 16; ++iter) {
        const int jb = iter * 256;
        float4 p0 = xp[jb + lane];
        float4 p1 = xp[jb + 64 + lane];
        float4 p2 = xp[jb + 128 + lane];
        float4 p3 = xp[jb + 192 + lane];
        float d0 = pi.w + p0.w - 2.0f * (pi.x * p0.x + pi.y * p0.y + pi.z * p0.z);
        float d1 = pi.w + p1.w - 2.0f * (pi.x * p1.x + pi.y * p1.y + pi.z * p1.z);
        float d2 = pi.w + p2.w - 2.0f * (pi.x * p2.x + pi.y * p2.y + pi.z * p2.z);
        float d3 = pi.w + p3.w - 2.0f * (pi.x * p3.x + pi.y * p3.y + pi.z * p3.z);
#pragma unroll
        for (int t = 0; t < 4; ++t) {
            float d = (t == 0) ? d0 : (t == 1) ? d1 : (t == 2) ? d2 : d3;
            int j = jb + t * 64 + lane;
            bool pred = (d < tau) && (j != i);
            unsigned long long m = __ballot(pred);
            if (pred) { int s = cnt + mbcnt64(m); cd[w][s] = d; ci[w][s] = j; }
            cnt += __popcll(m);
        }
        if (cnt > KBUF - 256) compact();   // fires at iter 0 (establishes tau); rare afterwards
    }
    compact();
    if (lane < KNN) knn_idx[i * KNN + lane] = wi;
}

// ---------------- DevConv max-agg + Wp/Wq/Wk (fused, block = 1 wave per node) ----------------
__global__ __launch_bounds__(64) void k_agg_feat_qk(const float4* __restrict__ xp, const int* __restrict__ edges,
                                                    const int* __restrict__ rowptr, const int* __restrict__ eidR,
                                                    const int* __restrict__ knn_idx, const float* __restrict__ Wt,
                                                    const float* __restrict__ Wp, const float* __restrict__ Wq,
                                                    const float* __restrict__ Wk,
                                                    float* __restrict__ qb, float* __restrict__ kb) {
    int i = blockIdx.x, h = threadIdx.x;
    __shared__ float mrow[H], frow[H];
    float w0 = Wt[h * 3], w1 = Wt[h * 3 + 1], w2 = Wt[h * 3 + 2];
    float4 pi = xp[i];
    float m = -INFINITY;
    int s0 = rowptr[i], s1 = rowptr[i + 1];
    for (int s = s0; s < s1; ++s) {
        int e = eidR[s];
        float4 pj = xp[edges[NE + e]];
        m = fmaxf(m, w0 * (pj.x - pi.x) + w1 * (pj.y - pi.y) + w2 * (pj.z - pi.z));
    }
    for (int t = 0; t < KNN; ++t) {
        float4 pj = xp[knn_idx[i * KNN + t]];
        m = fmaxf(m, w0 * (pj.x - pi.x) + w1 * (pj.y - pi.y) + w2 * (pj.z - pi.z));
    }
    if (!(m > -INFINITY)) m = 0.0f;
    mrow[h] = m;
    __syncthreads();
    float f = 0.f;
    for (int k2 = 0; k2 < H; ++k2) f += Wp[h * H + k2] * mrow[k2];
    frow[h] = f;
    __syncthreads();
    float qv = 0.f, kv = 0.f;
    for (int k2 = 0; k2 < H; ++k2) {
        float fr = frow[k2];
        qv += Wq[h * H + k2] * fr;
        kv += Wk[h * H + k2] * fr;
    }
    qb[i * H + h] = qv;
    kb[i * H + h] = kv;
}

// ---------------- attention scores: 1 wave per original edge ----------------
__global__ __launch_bounds__(256) void k_att(const int* __restrict__ edges, const float* __restrict__ qb,
                                             const float* __restrict__ kb, float* __restrict__ att) {
    int wid = (blockIdx.x * blockDim.x + threadIdx.x) >> 6;
    int lane = threadIdx.x & 63;
    if (wid >= NE) return;
    int r = edges[wid], c = edges[NE + wid];
    float v = qb[r * H + lane] * kb[c * H + lane];
#pragma unroll
    for (int o = 32; o > 0; o >>= 1) v += __shfl_xor(v, o);
    if (lane == 0) att[wid] = v;
}

// ---------------- segment softmax: 1 thread per node ----------------
__global__ void k_softmax(const int* __restrict__ rowptr, const int* __restrict__ eidR,
                          const float* __restrict__ att, float* __restrict__ attn) {
    int i = blockIdx.x * blockDim.x + threadIdx.x;
    if (i >= N_NODES) return;
    int s0 = rowptr[i], s1 = rowptr[i + 1];
    float m = -INFINITY;
    for (int s = s0; s < s1; ++s) m = fmaxf(m, att[eidR[s]]);
    float den = 0.f;
    for (int s = s0; s < s1; ++s) den += expf(att[eidR[s]] - m);
    for (int s = s0; s < s1; ++s) { int e = eidR[s]; attn[e] = expf(att[e] - m) / den; }
}

// ---------------- fill: CSC leaf prep (jv/av) + row-grouped pair list ----------------
__global__ void k_fill(const int* __restrict__ edges, const int* __restrict__ rowptr,
                       const int* __restrict__ eidR, const int* __restrict__ eidC,
                       const int* __restrict__ poff, const float* __restrict__ attn,
                       int* __restrict__ jv, float* __restrict__ av,
                       int* __restrict__ pairC2, float* __restrict__ pairSV) {
    int t = blockIdx.x * blockDim.x + threadIdx.x;
    if (t >= NE) return;
    // job A: CSC leaf prep
    int e3 = eidC[t];
    jv[t] = edges[e3];
    av[t] = attn[e3];
    // job B: pair fill for CSR slot t
    int e1 = eidR[t];
    int c = edges[NE + e1];
    float sv = attn[e1];
    int o = poff[t];
    int a0 = rowptr[c], a1 = rowptr[c + 1];
    for (int a = a0; a < a1; ++a) {
        int c2 = edges[NE + eidR[a]];
        pairC2[o] = c2; pairSV[o] = sv;
        ++o;
    }
}

// ---------------- final: block per output row, LDS accumulator, no global atomics ----------------
__global__ __launch_bounds__(256) void k_final_row(const int* __restrict__ rowptr,
                                                   const int* __restrict__ colptr,
                                                   const int* __restrict__ poff,
                                                   const int* __restrict__ pairC2, const float* __restrict__ pairSV,
                                                   const int* __restrict__ jv, const float* __restrict__ av,
                                                   float* __restrict__ out) {
    __shared__ __align__(16) float Orow[N_NODES];
    int r = blockIdx.x;
    int tid = threadIdx.x;
    float4* O4 = (float4*)Orow;
    float4 z = {0.f, 0.f, 0.f, 0.f};
#pragma unroll
    for (int t = 0; t < N_NODES / 4 / 256; ++t) O4[tid + t * 256] = z;
    __syncthreads();

    int pr0 = poff[rowptr[r]], pr1 = poff[rowptr[r + 1]];
    for (int p = pr0 + tid; p < pr1; p += 256) {
        int c2 = pairC2[p];
        float sv = pairSV[p];
        int b0 = colptr[c2], b1 = colptr[c2 + 1];
        for (int b = b0; b < b1; ++b) {
            atomicAdd(&Orow[jv[b]], sv * av[b]);
        }
    }
    __syncthreads();

    float4* o4 = (float4*)(out + (size_t)r * N_NODES);
#pragma unroll
    for (int t = 0; t < N_NODES / 4 / 256; ++t) o4[tid + t * 256] = O4[tid + t * 256];
}

extern "C" void kernel_launch(void* const* d_in, const int* in_sizes, int n_in,
                              void* d_out, int out_size, void* d_ws, size_t ws_size,
                              hipStream_t stream) {
    const float* x    = (const float*)d_in[0];
    const int* edges  = (const int*)d_in[1];
    const float* Wt   = (const float*)d_in[2];
    const float* Wp   = (const float*)d_in[3];
    const float* Wq   = (const float*)d_in[4];
    const float* Wk   = (const float*)d_in[5];
    float* out = (float*)d_out;

    char* w = (char*)d_ws;
    size_t off = 0;
    auto alloc = [&](size_t bytes) -> void* {
        void* p = w + off;
        off += (bytes + 255) & ~(size_t)255;
        return p;
    };
    float4* xp    = (float4*)alloc((size_t)N_NODES * 16);
    int*   knn    = (int*)  alloc((size_t)N_NODES * KNN * 4);
    float* qb     = (float*)alloc((size_t)N_NODES * H * 4);
    float* kb     = (float*)alloc((size_t)N_NODES * H * 4);
    float* att    = (float*)alloc((size_t)NE * 4);
    float* attn   = (float*)alloc((size_t)NE * 4);
    int*   degR   = (int*)  alloc((size_t)N_NODES * 4);
    int*   degC   = (int*)  alloc((size_t)N_NODES * 4);
    int*   rowptr = (int*)  alloc((size_t)(N_NODES + 4) * 4);
    int*   colptr = (int*)  alloc((size_t)(N_NODES + 4) * 4);
    int*   cursR  = (int*)  alloc((size_t)N_NODES * 4);
    int*   cursC  = (int*)  alloc((size_t)N_NODES * 4);
    int*   eidR   = (int*)  alloc((size_t)NE * 4);
    int*   eidC   = (int*)  alloc((size_t)NE * 4);
    int*   pcnt2  = (int*)  alloc((size_t)NE * 4);
    int*   poff   = (int*)  alloc((size_t)(NE + 1) * 4);
    int*   jv     = (int*)  alloc((size_t)NE * 4);
    float* av     = (float*)alloc((size_t)NE * 4);
    int*   pairC2 = (int*)  alloc((size_t)MAXPAIRS * 4);
    float* pairSV = (float*)alloc((size_t)MAXPAIRS * 4);

    k_init2<<<(N_NODES + 255) / 256, 256, 0, stream>>>(degR, degC, x, xp);
    k_hist<<<(NE + 255) / 256, 256, 0, stream>>>(edges, degR, degC);
    k_knn<<<N_NODES / 4, 256, 0, stream>>>(xp, knn);
    k_scan2<<<1, 128, 0, stream>>>(degR, degC, rowptr, colptr, cursR, cursC);
    k_scatter<<<(NE + 255) / 256, 256, 0, stream>>>(edges, rowptr, cursR, cursC, eidR, eidC, pcnt2);
    k_pscan<<<1, 1024, 0, stream>>>(pcnt2, poff);
    k_agg_feat_qk<<<N_NODES, 64, 0, stream>>>(xp, edges, rowptr, eidR, knn, Wt, Wp, Wq, Wk, qb, kb);
    k_att<<<(NE * 64) / 256, 256, 0, stream>>>(edges, qb, kb, att);
    k_softmax<<<(N_NODES + 255) / 256, 256, 0, stream>>>(rowptr, eidR, att, attn);
    k_fill<<<(NE + 255) / 256, 256, 0, stream>>>(edges, rowptr, eidR, eidC, poff, attn, jv, av, pairC2, pairSV);
    k_final_row<<<N_NODES, 256, 0, stream>>>(rowptr, colptr, poff, pairC2, pairSV, jv, av, out);
}

// Round 8
// 148.039 us; speedup vs baseline: 1.7881x; 1.0204x over previous
//
#include <hip/hip_runtime.h>
#include <math.h>

#define N_NODES 4096
#define H 64
#define NE 24576
#define KNN 15
#define KBUF 448
#define MAXPAIRS 393216

__device__ __forceinline__ int mbcnt64(unsigned long long m) {
    int lo = __builtin_amdgcn_mbcnt_lo((unsigned int)m, 0u);
    return __builtin_amdgcn_mbcnt_hi((unsigned int)(m >> 32), lo);
}

// ---------------- init: deg counters + xp = (x,y,z,|x|^2) ----------------
__global__ __launch_bounds__(256) void k_init2(int* __restrict__ degR, int* __restrict__ degC,
                                               const float* __restrict__ x, float4* __restrict__ xp) {
    int tid = blockIdx.x * 256 + threadIdx.x;
    if (tid < N_NODES) {
        degR[tid] = 0; degC[tid] = 0;
        float a = x[tid * 3], b = x[tid * 3 + 1], c = x[tid * 3 + 2];
        xp[tid] = make_float4(a, b, c, a * a + b * b + c * c);
    }
}

// ---------------- histogram of original edges ----------------
__global__ void k_hist(const int* __restrict__ edges, int* degR, int* degC) {
    int e = blockIdx.x * blockDim.x + threadIdx.x;
    if (e < NE) {
        atomicAdd(&degR[edges[e]], 1);
        atomicAdd(&degC[edges[NE + e]], 1);
    }
}

// ---------------- barrier-free scan: wave0 -> rowptr/cursR, wave1 -> colptr/cursC ----------------
__global__ __launch_bounds__(128) void k_scan2(const int* __restrict__ degR, const int* __restrict__ degC,
                                               int* rowptr, int* colptr, int* cursR, int* cursC) {
    int w = threadIdx.x >> 6, lane = threadIdx.x & 63;
    const int* deg = w ? degC : degR;
    int* ptr  = w ? colptr : rowptr;
    int* curs = w ? cursC : cursR;
    const int4* d4 = (const int4*)deg + lane * 16;
    int4 v[16];
    int s = 0;
#pragma unroll
    for (int t = 0; t < 16; ++t) { v[t] = d4[t]; s += v[t].x + v[t].y + v[t].z + v[t].w; }
    int incl = s;
#pragma unroll
    for (int o = 1; o < 64; o <<= 1) { int u = __shfl_up(incl, o); if (lane >= o) incl += u; }
    int run = incl - s;
    int4* p4 = (int4*)ptr + lane * 16;
    int4* c4 = (int4*)curs + lane * 16;
#pragma unroll
    for (int t = 0; t < 16; ++t) {
        int4 o;
        o.x = run; run += v[t].x;
        o.y = run; run += v[t].y;
        o.z = run; run += v[t].z;
        o.w = run; run += v[t].w;
        p4[t] = o; c4[t] = o;
    }
    if (lane == 63) ptr[N_NODES] = run;
}

// ---------------- scatter edge ids into CSR/CSC; pair-count per CSR slot ----------------
__global__ void k_scatter(const int* __restrict__ edges, const int* __restrict__ rowptr,
                          int* cursR, int* cursC, int* eidR, int* eidC, int* pcnt2) {
    int e = blockIdx.x * blockDim.x + threadIdx.x;
    if (e < NE) {
        int r = edges[e], c = edges[NE + e];
        int p = atomicAdd(&cursR[r], 1); eidR[p] = e;
        int q = atomicAdd(&cursC[c], 1); eidC[q] = e;
        pcnt2[p] = rowptr[c + 1] - rowptr[c];   // pairs spawned by this CSR slot
    }
}

// ---------------- scan of pair counts over CSR slots (one block, 1024 x 24) ----------------
__global__ __launch_bounds__(1024) void k_pscan(const int* __restrict__ pcnt2, int* __restrict__ poff) {
    __shared__ int buf[1024];
    int t = threadIdx.x;
    int v[24];
    int s = 0;
    int base = t * 24;
#pragma unroll
    for (int k2 = 0; k2 < 24; ++k2) { v[k2] = pcnt2[base + k2]; s += v[k2]; }
    buf[t] = s;
    __syncthreads();
    int acc = s;
    for (int o = 1; o < 1024; o <<= 1) {
        int other = (t >= o) ? buf[t - o] : 0;
        __syncthreads();
        acc += other;
        buf[t] = acc;
        __syncthreads();
    }
    int run = acc - s;  // exclusive
#pragma unroll
    for (int k2 = 0; k2 < 24; ++k2) { poff[base + k2] = run; run += v[k2]; }
    if (t == 1023) poff[NE] = run;
}

// ---------------- kNN: wave per node, packed u64 (dist_bits<<32)|idx keys ----------------
// Order of the 15 output neighbors is irrelevant downstream (max-agg + incidence),
// so selection (not sorting) suffices; min over packed keys = lowest-index tie-break.
__global__ __launch_bounds__(256) void k_knn(const float4* __restrict__ xp, int* __restrict__ knn_idx) {
    __shared__ unsigned long long cb[4][KBUF];
    const int w = threadIdx.x >> 6;
    const int lane = threadIdx.x & 63;
    const int i = blockIdx.x * 4 + w;
    const float4 pi = xp[i];
    unsigned long long tauKey = ~0ull;
    unsigned long long win = ~0ull;   // lane r (<15) holds r-th winner after compact
    int cnt = 0;

    // top-KNN of cb[w][0..cnt) by key; winners -> win (lanes 0..14) + slots 0..14; tau = 15th
    auto compact = [&]() {
        __builtin_amdgcn_wave_barrier();
        unsigned long long v[7];
#pragma unroll
        for (int t = 0; t < 7; ++t) {
            v[t] = ~0ull;
            if (t * 64 < cnt) {                 // wave-uniform skip of dead regs
                int s = t * 64 + lane;
                if (s < cnt) v[t] = cb[w][s];
            }
        }
        unsigned long long bd = ~0ull;
        for (int r = 0; r < KNN; ++r) {
            bd = v[0];
#pragma unroll
            for (int t = 1; t < 7; ++t) bd = (v[t] < bd) ? v[t] : bd;
#pragma unroll
            for (int o = 32; o > 0; o >>= 1) {
                unsigned long long od = __shfl_xor(bd, o);
                bd = (od < bd) ? od : bd;
            }
            if (lane == r) win = bd;
            // remove winner (keys unique: low 32 bits = candidate index)
#pragma unroll
            for (int t = 0; t < 7; ++t) v[t] = (v[t] == bd) ? ~0ull : v[t];
        }
        __builtin_amdgcn_wave_barrier();
        if (lane < KNN) cb[w][lane] = win;
        cnt = KNN;
        tauKey = bd;                            // 15th smallest key, wave-uniform
        __builtin_amdgcn_wave_barrier();
    };

    // iter 0: unconditional append of 256 candidates (self -> ~0ull), no ballot
    {
        float4 p0 = xp[lane];
        float4 p1 = xp[64 + lane];
        float4 p2 = xp[128 + lane];
        float4 p3 = xp[192 + lane];
        float d0 = pi.w + p0.w - 2.0f * (pi.x * p0.x + pi.y * p0.y + pi.z * p0.z);
        float d1 = pi.w + p1.w - 2.0f * (pi.x * p1.x + pi.y * p1.y + pi.z * p1.z);
        float d2 = pi.w + p2.w - 2.0f * (pi.x * p2.x + pi.y * p2.y + pi.z * p2.z);
        float d3 = pi.w + p3.w - 2.0f * (pi.x * p3.x + pi.y * p3.y + pi.z * p3.z);
#pragma unroll
        for (int t = 0; t < 4; ++t) {
            float d = (t == 0) ? d0 : (t == 1) ? d1 : (t == 2) ? d2 : d3;
            int j = t * 64 + lane;
            unsigned long long key = ((unsigned long long)__float_as_uint(d) << 32) | (unsigned)j;
            if (j == i) key = ~0ull;
            cb[w][j] = key;
        }
        cnt = 256;
        compact();
    }

    // iters 1..15: filtered rare append
    for (int iter = 1; iter < 16; ++iter) {
        const int jb = iter * 256;
        float4 p0 = xp[jb + lane];
        float4 p1 = xp[jb + 64 + lane];
        float4 p2 = xp[jb + 128 + lane];
        float4 p3 = xp[jb + 192 + lane];
        float d0 = pi.w + p0.w - 2.0f * (pi.x * p0.x + pi.y * p0.y + pi.z * p0.z);
        float d1 = pi.w + p1.w - 2.0f * (pi.x * p1.x + pi.y * p1.y + pi.z * p1.z);
        float d2 = pi.w + p2.w - 2.0f * (pi.x * p2.x + pi.y * p2.y + pi.z * p2.z);
        float d3 = pi.w + p3.w - 2.0f * (pi.x * p3.x + pi.y * p3.y + pi.z * p3.z);
#pragma unroll
        for (int t = 0; t < 4; ++t) {
            float d = (t == 0) ? d0 : (t == 1) ? d1 : (t == 2) ? d2 : d3;
            int j = jb + t * 64 + lane;
            unsigned long long key = ((unsigned long long)__float_as_uint(d) << 32) | (unsigned)j;
            bool pred = (key < tauKey) && (j != i);
            unsigned long long m = __ballot(pred);
            if (m) {
                if (pred) cb[w][cnt + mbcnt64(m)] = key;
                cnt += __popcll(m);
            }
        }
        if (cnt > KBUF - 256) compact();   // statistically never fires; guarantees no overflow
    }
    compact();
    if (lane < KNN) knn_idx[i * KNN + lane] = (int)(win & 0xffffffffu);
}

// ---------------- DevConv max-agg + Wp/Wq/Wk (fused, block = 1 wave per node) ----------------
__global__ __launch_bounds__(64) void k_agg_feat_qk(const float4* __restrict__ xp, const int* __restrict__ edges,
                                                    const int* __restrict__ rowptr, const int* __restrict__ eidR,
                                                    const int* __restrict__ knn_idx, const float* __restrict__ Wt,
                                                    const float* __restrict__ Wp, const float* __restrict__ Wq,
                                                    const float* __restrict__ Wk,
                                                    float* __restrict__ qb, float* __restrict__ kb) {
    int i = blockIdx.x, h = threadIdx.x;
    __shared__ float mrow[H], frow[H];
    float w0 = Wt[h * 3], w1 = Wt[h * 3 + 1], w2 = Wt[h * 3 + 2];
    float4 pi = xp[i];
    float m = -INFINITY;
    int s0 = rowptr[i], s1 = rowptr[i + 1];
    for (int s = s0; s < s1; ++s) {
        int e = eidR[s];
        float4 pj = xp[edges[NE + e]];
        m = fmaxf(m, w0 * (pj.x - pi.x) + w1 * (pj.y - pi.y) + w2 * (pj.z - pi.z));
    }
    for (int t = 0; t < KNN; ++t) {
        float4 pj = xp[knn_idx[i * KNN + t]];
        m = fmaxf(m, w0 * (pj.x - pi.x) + w1 * (pj.y - pi.y) + w2 * (pj.z - pi.z));
    }
    if (!(m > -INFINITY)) m = 0.0f;
    mrow[h] = m;
    __syncthreads();
    float f = 0.f;
    for (int k2 = 0; k2 < H; ++k2) f += Wp[h * H + k2] * mrow[k2];
    frow[h] = f;
    __syncthreads();
    float qv = 0.f, kv = 0.f;
    for (int k2 = 0; k2 < H; ++k2) {
        float fr = frow[k2];
        qv += Wq[h * H + k2] * fr;
        kv += Wk[h * H + k2] * fr;
    }
    qb[i * H + h] = qv;
    kb[i * H + h] = kv;
}

// ---------------- attention scores: 1 wave per original edge ----------------
__global__ __launch_bounds__(256) void k_att(const int* __restrict__ edges, const float* __restrict__ qb,
                                             const float* __restrict__ kb, float* __restrict__ att) {
    int wid = (blockIdx.x * blockDim.x + threadIdx.x) >> 6;
    int lane = threadIdx.x & 63;
    if (wid >= NE) return;
    int r = edges[wid], c = edges[NE + wid];
    float v = qb[r * H + lane] * kb[c * H + lane];
#pragma unroll
    for (int o = 32; o > 0; o >>= 1) v += __shfl_xor(v, o);
    if (lane == 0) att[wid] = v;
}

// ---------------- segment softmax: 1 thread per node ----------------
__global__ void k_softmax(const int* __restrict__ rowptr, const int* __restrict__ eidR,
                          const float* __restrict__ att, float* __restrict__ attn) {
    int i = blockIdx.x * blockDim.x + threadIdx.x;
    if (i >= N_NODES) return;
    int s0 = rowptr[i], s1 = rowptr[i + 1];
    float m = -INFINITY;
    for (int s = s0; s < s1; ++s) m = fmaxf(m, att[eidR[s]]);
    float den = 0.f;
    for (int s = s0; s < s1; ++s) den += expf(att[eidR[s]] - m);
    for (int s = s0; s < s1; ++s) { int e = eidR[s]; attn[e] = expf(att[e] - m) / den; }
}

// ---------------- fill: CSC leaf prep (jv/av) + row-grouped pair list ----------------
__global__ void k_fill(const int* __restrict__ edges, const int* __restrict__ rowptr,
                       const int* __restrict__ eidR, const int* __restrict__ eidC,
                       const int* __restrict__ poff, const float* __restrict__ attn,
                       int* __restrict__ jv, float* __restrict__ av,
                       int* __restrict__ pairC2, float* __restrict__ pairSV) {
    int t = blockIdx.x * blockDim.x + threadIdx.x;
    if (t >= NE) return;
    // job A: CSC leaf prep
    int e3 = eidC[t];
    jv[t] = edges[e3];
    av[t] = attn[e3];
    // job B: pair fill for CSR slot t
    int e1 = eidR[t];
    int c = edges[NE + e1];
    float sv = attn[e1];
    int o = poff[t];
    int a0 = rowptr[c], a1 = rowptr[c + 1];
    for (int a = a0; a < a1; ++a) {
        int c2 = edges[NE + eidR[a]];
        pairC2[o] = c2; pairSV[o] = sv;
        ++o;
    }
}

// ---------------- final: block per output row, LDS accumulator, no global atomics ----------------
__global__ __launch_bounds__(256) void k_final_row(const int* __restrict__ rowptr,
                                                   const int* __restrict__ colptr,
                                                   const int* __restrict__ poff,
                                                   const int* __restrict__ pairC2, const float* __restrict__ pairSV,
                                                   const int* __restrict__ jv, const float* __restrict__ av,
                                                   float* __restrict__ out) {
    __shared__ __align__(16) float Orow[N_NODES];
    int r = blockIdx.x;
    int tid = threadIdx.x;
    float4* O4 = (float4*)Orow;
    float4 z = {0.f, 0.f, 0.f, 0.f};
#pragma unroll
    for (int t = 0; t < N_NODES / 4 / 256; ++t) O4[tid + t * 256] = z;
    __syncthreads();

    int pr0 = poff[rowptr[r]], pr1 = poff[rowptr[r + 1]];
    for (int p = pr0 + tid; p < pr1; p += 256) {
        int c2 = pairC2[p];
        float sv = pairSV[p];
        int b0 = colptr[c2], b1 = colptr[c2 + 1];
        for (int b = b0; b < b1; ++b) {
            atomicAdd(&Orow[jv[b]], sv * av[b]);
        }
    }
    __syncthreads();

    float4* o4 = (float4*)(out + (size_t)r * N_NODES);
#pragma unroll
    for (int t = 0; t < N_NODES / 4 / 256; ++t) o4[tid + t * 256] = O4[tid + t * 256];
}

extern "C" void kernel_launch(void* const* d_in, const int* in_sizes, int n_in,
                              void* d_out, int out_size, void* d_ws, size_t ws_size,
                              hipStream_t stream) {
    const float* x    = (const float*)d_in[0];
    const int* edges  = (const int*)d_in[1];
    const float* Wt   = (const float*)d_in[2];
    const float* Wp   = (const float*)d_in[3];
    const float* Wq   = (const float*)d_in[4];
    const float* Wk   = (const float*)d_in[5];
    float* out = (float*)d_out;

    char* w = (char*)d_ws;
    size_t off = 0;
    auto alloc = [&](size_t bytes) -> void* {
        void* p = w + off;
        off += (bytes + 255) & ~(size_t)255;
        return p;
    };
    float4* xp    = (float4*)alloc((size_t)N_NODES * 16);
    int*   knn    = (int*)  alloc((size_t)N_NODES * KNN * 4);
    float* qb     = (float*)alloc((size_t)N_NODES * H * 4);
    float* kb     = (float*)alloc((size_t)N_NODES * H * 4);
    float* att    = (float*)alloc((size_t)NE * 4);
    float* attn   = (float*)alloc((size_t)NE * 4);
    int*   degR   = (int*)  alloc((size_t)N_NODES * 4);
    int*   degC   = (int*)  alloc((size_t)N_NODES * 4);
    int*   rowptr = (int*)  alloc((size_t)(N_NODES + 4) * 4);
    int*   colptr = (int*)  alloc((size_t)(N_NODES + 4) * 4);
    int*   cursR  = (int*)  alloc((size_t)N_NODES * 4);
    int*   cursC  = (int*)  alloc((size_t)N_NODES * 4);
    int*   eidR   = (int*)  alloc((size_t)NE * 4);
    int*   eidC   = (int*)  alloc((size_t)NE * 4);
    int*   pcnt2  = (int*)  alloc((size_t)NE * 4);
    int*   poff   = (int*)  alloc((size_t)(NE + 1) * 4);
    int*   jv     = (int*)  alloc((size_t)NE * 4);
    float* av     = (float*)alloc((size_t)NE * 4);
    int*   pairC2 = (int*)  alloc((size_t)MAXPAIRS * 4);
    float* pairSV = (float*)alloc((size_t)MAXPAIRS * 4);

    k_init2<<<(N_NODES + 255) / 256, 256, 0, stream>>>(degR, degC, x, xp);
    k_hist<<<(NE + 255) / 256, 256, 0, stream>>>(edges, degR, degC);
    k_knn<<<N_NODES / 4, 256, 0, stream>>>(xp, knn);
    k_scan2<<<1, 128, 0, stream>>>(degR, degC, rowptr, colptr, cursR, cursC);
    k_scatter<<<(NE + 255) / 256, 256, 0, stream>>>(edges, rowptr, cursR, cursC, eidR, eidC, pcnt2);
    k_pscan<<<1, 1024, 0, stream>>>(pcnt2, poff);
    k_agg_feat_qk<<<N_NODES, 64, 0, stream>>>(xp, edges, rowptr, eidR, knn, Wt, Wp, Wq, Wk, qb, kb);
    k_att<<<(NE * 64) / 256, 256, 0, stream>>>(edges, qb, kb, att);
    k_softmax<<<(N_NODES + 255) / 256, 256, 0, stream>>>(rowptr, eidR, att, attn);
    k_fill<<<(NE + 255) / 256, 256, 0, stream>>>(edges, rowptr, eidR, eidC, poff, attn, jv, av, pairC2, pairSV);
    k_final_row<<<N_NODES, 256, 0, stream>>>(rowptr, colptr, poff, pairC2, pairSV, jv, av, out);
}

// Round 9
// 124.508 us; speedup vs baseline: 2.1260x; 1.1890x over previous
//
#include <hip/hip_runtime.h>
#include <math.h>

#define N_NODES 4096
#define H 64
#define NE 24576
#define KNN 15
#define KBUF 448
#define MAXPAIRS 393216

__device__ __forceinline__ int mbcnt64(unsigned long long m) {
    int lo = __builtin_amdgcn_mbcnt_lo((unsigned int)m, 0u);
    return __builtin_amdgcn_mbcnt_hi((unsigned int)(m >> 32), lo);
}

// ---------------- init: deg counters + xp = (x,y,z,|x|^2) ----------------
__global__ __launch_bounds__(256) void k_init2(int* __restrict__ degR, int* __restrict__ degC,
                                               const float* __restrict__ x, float4* __restrict__ xp) {
    int tid = blockIdx.x * 256 + threadIdx.x;
    if (tid < N_NODES) {
        degR[tid] = 0; degC[tid] = 0;
        float a = x[tid * 3], b = x[tid * 3 + 1], c = x[tid * 3 + 2];
        xp[tid] = make_float4(a, b, c, a * a + b * b + c * c);
    }
}

// ---------------- histogram of original edges ----------------
__global__ void k_hist(const int* __restrict__ edges, int* degR, int* degC) {
    int e = blockIdx.x * blockDim.x + threadIdx.x;
    if (e < NE) {
        atomicAdd(&degR[edges[e]], 1);
        atomicAdd(&degC[edges[NE + e]], 1);
    }
}

// ---------------- barrier-free scan: wave0 -> rowptr/cursR, wave1 -> colptr/cursC ----------------
__global__ __launch_bounds__(128) void k_scan2(const int* __restrict__ degR, const int* __restrict__ degC,
                                               int* rowptr, int* colptr, int* cursR, int* cursC) {
    int w = threadIdx.x >> 6, lane = threadIdx.x & 63;
    const int* deg = w ? degC : degR;
    int* ptr  = w ? colptr : rowptr;
    int* curs = w ? cursC : cursR;
    const int4* d4 = (const int4*)deg + lane * 16;
    int4 v[16];
    int s = 0;
#pragma unroll
    for (int t = 0; t < 16; ++t) { v[t] = d4[t]; s += v[t].x + v[t].y + v[t].z + v[t].w; }
    int incl = s;
#pragma unroll
    for (int o = 1; o < 64; o <<= 1) { int u = __shfl_up(incl, o); if (lane >= o) incl += u; }
    int run = incl - s;
    int4* p4 = (int4*)ptr + lane * 16;
    int4* c4 = (int4*)curs + lane * 16;
#pragma unroll
    for (int t = 0; t < 16; ++t) {
        int4 o;
        o.x = run; run += v[t].x;
        o.y = run; run += v[t].y;
        o.z = run; run += v[t].z;
        o.w = run; run += v[t].w;
        p4[t] = o; c4[t] = o;
    }
    if (lane == 63) ptr[N_NODES] = run;
}

// ---------------- scatter edge ids into CSR/CSC; pair-count per CSR slot ----------------
__global__ void k_scatter(const int* __restrict__ edges, const int* __restrict__ rowptr,
                          int* cursR, int* cursC, int* eidR, int* eidC, int* pcnt2) {
    int e = blockIdx.x * blockDim.x + threadIdx.x;
    if (e < NE) {
        int r = edges[e], c = edges[NE + e];
        int p = atomicAdd(&cursR[r], 1); eidR[p] = e;
        int q = atomicAdd(&cursC[c], 1); eidC[q] = e;
        pcnt2[p] = rowptr[c + 1] - rowptr[c];   // pairs spawned by this CSR slot
    }
}

// ---------------- scan of pair counts over CSR slots (one block, 1024 x 24) ----------------
__global__ __launch_bounds__(1024) void k_pscan(const int* __restrict__ pcnt2, int* __restrict__ poff) {
    __shared__ int buf[1024];
    int t = threadIdx.x;
    int v[24];
    int s = 0;
    int base = t * 24;
#pragma unroll
    for (int k2 = 0; k2 < 24; ++k2) { v[k2] = pcnt2[base + k2]; s += v[k2]; }
    buf[t] = s;
    __syncthreads();
    int acc = s;
    for (int o = 1; o < 1024; o <<= 1) {
        int other = (t >= o) ? buf[t - o] : 0;
        __syncthreads();
        acc += other;
        buf[t] = acc;
        __syncthreads();
    }
    int run = acc - s;  // exclusive
#pragma unroll
    for (int k2 = 0; k2 < 24; ++k2) { poff[base + k2] = run; run += v[k2]; }
    if (t == 1023) poff[NE] = run;
}

// ---------------- kNN: wave per node, u64 keys, bitonic-sort selection ----------------
// key = (dist_bits<<32)|j : unique, min-order = (dist, lowest index). Neighbor order is
// irrelevant downstream (max-agg + incidence), only the exact SET matters.
__global__ __launch_bounds__(256) void k_knn(const float4* __restrict__ xp, int* __restrict__ knn_idx) {
    __shared__ unsigned long long cb[4][KBUF];
    const int w = threadIdx.x >> 6;
    const int lane = threadIdx.x & 63;
    const int i = blockIdx.x * 4 + w;
    const float4 pi = xp[i];
    unsigned long long tauKey;
    int cnt;

    // full 64-lane bitonic sort (ascending); returns lane's sorted value
    auto sort64 = [&](unsigned long long key) -> unsigned long long {
#pragma unroll
        for (int k = 2; k <= 64; k <<= 1) {
#pragma unroll
            for (int j = 32; j > 0; j >>= 1) {
                if (j >= k) continue;
                unsigned long long other = __shfl_xor(key, j);
                bool asc = ((lane & k) == 0);
                bool takeMin = (((lane & j) == 0) == asc);
                bool less = key < other;
                key = (takeMin == less) ? key : other;
            }
        }
        return key;
    };

    // tighten: survivors (key <= T, T = 15th-smallest lane-min, upper bound on exact 15th)
    // compacted to cb[w][0..cnt'). Guarantees cnt' >= 15 and keeps all true top-15.
    auto tighten = [&]() {
        __builtin_amdgcn_wave_barrier();
        int n = (cnt + 63) >> 6;
        unsigned long long v[7];
        unsigned long long kmin = ~0ull;
#pragma unroll
        for (int t = 0; t < 7; ++t) {
            v[t] = ~0ull;
            if (t < n) {
                int s = t * 64 + lane;
                if (s < cnt) v[t] = cb[w][s];
                kmin = (v[t] < kmin) ? v[t] : kmin;
            }
        }
        unsigned long long T = __shfl(sort64(kmin), 14);
        __builtin_amdgcn_wave_barrier();
        int m = 0;
#pragma unroll
        for (int t = 0; t < 7; ++t) {
            if (t < n) {
                bool pred = (v[t] <= T);
                unsigned long long mk = __ballot(pred);
                if (pred) cb[w][m + mbcnt64(mk)] = v[t];
                m += __popcll(mk);
            }
        }
        cnt = m;
        tauKey = T;
        __builtin_amdgcn_wave_barrier();
    };

    // iter 0: store all 256 keys; tau from sorted lane-mins (upper bound on exact 15th)
    {
        unsigned long long kmin = ~0ull;
#pragma unroll
        for (int t = 0; t < 4; ++t) {
            int j = t * 64 + lane;
            float4 pj = xp[j];
            float d = pi.w + pj.w - 2.0f * (pi.x * pj.x + pi.y * pj.y + pi.z * pj.z);
            unsigned long long key = ((unsigned long long)__float_as_uint(d) << 32) | (unsigned)j;
            if (j == i) key = ~0ull;
            cb[w][j] = key;
            kmin = (key < kmin) ? key : kmin;
        }
        cnt = 256;
        tauKey = __shfl(sort64(kmin), 14);
        __builtin_amdgcn_wave_barrier();
    }

    // iters 1..15: filtered append (key < tau keeps every true top-15 key; tau is in buffer)
    for (int iter = 1; iter < 16; ++iter) {
        const int jb = iter * 256;
        float4 p0 = xp[jb + lane];
        float4 p1 = xp[jb + 64 + lane];
        float4 p2 = xp[jb + 128 + lane];
        float4 p3 = xp[jb + 192 + lane];
        float d0 = pi.w + p0.w - 2.0f * (pi.x * p0.x + pi.y * p0.y + pi.z * p0.z);
        float d1 = pi.w + p1.w - 2.0f * (pi.x * p1.x + pi.y * p1.y + pi.z * p1.z);
        float d2 = pi.w + p2.w - 2.0f * (pi.x * p2.x + pi.y * p2.y + pi.z * p2.z);
        float d3 = pi.w + p3.w - 2.0f * (pi.x * p3.x + pi.y * p3.y + pi.z * p3.z);
#pragma unroll
        for (int t = 0; t < 4; ++t) {
            float d = (t == 0) ? d0 : (t == 1) ? d1 : (t == 2) ? d2 : d3;
            int j = jb + t * 64 + lane;
            unsigned long long key = ((unsigned long long)__float_as_uint(d) << 32) | (unsigned)j;
            bool pred = (key < tauKey) && (j != i);
            unsigned long long m = __ballot(pred);
            if (m) {
                if (pred) cb[w][cnt + mbcnt64(m)] = key;
                cnt += __popcll(m);
            }
        }
        if (cnt > KBUF - 256) tighten();   // statistically never fires; prevents overflow
    }

    // final: tighten to <=64 survivors (one repeat gives deterministic bound), sort, emit
    tighten();
    if (cnt > 64) tighten();
    unsigned long long fin = (lane < cnt) ? cb[w][lane] : ~0ull;
    fin = sort64(fin);
    if (lane < KNN) knn_idx[i * KNN + lane] = (int)(fin & 0xffffffffu);
}

// ---------------- DevConv max-agg + Wp/Wq/Wk (fused, block = 1 wave per node) ----------------
__global__ __launch_bounds__(64) void k_agg_feat_qk(const float4* __restrict__ xp, const int* __restrict__ edges,
                                                    const int* __restrict__ rowptr, const int* __restrict__ eidR,
                                                    const int* __restrict__ knn_idx, const float* __restrict__ Wt,
                                                    const float* __restrict__ Wp, const float* __restrict__ Wq,
                                                    const float* __restrict__ Wk,
                                                    float* __restrict__ qb, float* __restrict__ kb) {
    int i = blockIdx.x, h = threadIdx.x;
    __shared__ float mrow[H], frow[H];
    float w0 = Wt[h * 3], w1 = Wt[h * 3 + 1], w2 = Wt[h * 3 + 2];
    float4 pi = xp[i];
    float m = -INFINITY;
    int s0 = rowptr[i], s1 = rowptr[i + 1];
    for (int s = s0; s < s1; ++s) {
        int e = eidR[s];
        float4 pj = xp[edges[NE + e]];
        m = fmaxf(m, w0 * (pj.x - pi.x) + w1 * (pj.y - pi.y) + w2 * (pj.z - pi.z));
    }
    for (int t = 0; t < KNN; ++t) {
        float4 pj = xp[knn_idx[i * KNN + t]];
        m = fmaxf(m, w0 * (pj.x - pi.x) + w1 * (pj.y - pi.y) + w2 * (pj.z - pi.z));
    }
    if (!(m > -INFINITY)) m = 0.0f;
    mrow[h] = m;
    __syncthreads();
    float f = 0.f;
    for (int k2 = 0; k2 < H; ++k2) f += Wp[h * H + k2] * mrow[k2];
    frow[h] = f;
    __syncthreads();
    float qv = 0.f, kv = 0.f;
    for (int k2 = 0; k2 < H; ++k2) {
        float fr = frow[k2];
        qv += Wq[h * H + k2] * fr;
        kv += Wk[h * H + k2] * fr;
    }
    qb[i * H + h] = qv;
    kb[i * H + h] = kv;
}

// ---------------- attention scores: 1 wave per original edge ----------------
__global__ __launch_bounds__(256) void k_att(const int* __restrict__ edges, const float* __restrict__ qb,
                                             const float* __restrict__ kb, float* __restrict__ att) {
    int wid = (blockIdx.x * blockDim.x + threadIdx.x) >> 6;
    int lane = threadIdx.x & 63;
    if (wid >= NE) return;
    int r = edges[wid], c = edges[NE + wid];
    float v = qb[r * H + lane] * kb[c * H + lane];
#pragma unroll
    for (int o = 32; o > 0; o >>= 1) v += __shfl_xor(v, o);
    if (lane == 0) att[wid] = v;
}

// ---------------- segment softmax: 1 thread per node ----------------
__global__ void k_softmax(const int* __restrict__ rowptr, const int* __restrict__ eidR,
                          const float* __restrict__ att, float* __restrict__ attn) {
    int i = blockIdx.x * blockDim.x + threadIdx.x;
    if (i >= N_NODES) return;
    int s0 = rowptr[i], s1 = rowptr[i + 1];
    float m = -INFINITY;
    for (int s = s0; s < s1; ++s) m = fmaxf(m, att[eidR[s]]);
    float den = 0.f;
    for (int s = s0; s < s1; ++s) den += expf(att[eidR[s]] - m);
    for (int s = s0; s < s1; ++s) { int e = eidR[s]; attn[e] = expf(att[e] - m) / den; }
}

// ---------------- fill: CSC leaf prep (jv/av) + row-grouped pair list ----------------
__global__ void k_fill(const int* __restrict__ edges, const int* __restrict__ rowptr,
                       const int* __restrict__ eidR, const int* __restrict__ eidC,
                       const int* __restrict__ poff, const float* __restrict__ attn,
                       int* __restrict__ jv, float* __restrict__ av,
                       int* __restrict__ pairC2, float* __restrict__ pairSV) {
    int t = blockIdx.x * blockDim.x + threadIdx.x;
    if (t >= NE) return;
    // job A: CSC leaf prep
    int e3 = eidC[t];
    jv[t] = edges[e3];
    av[t] = attn[e3];
    // job B: pair fill for CSR slot t
    int e1 = eidR[t];
    int c = edges[NE + e1];
    float sv = attn[e1];
    int o = poff[t];
    int a0 = rowptr[c], a1 = rowptr[c + 1];
    for (int a = a0; a < a1; ++a) {
        int c2 = edges[NE + eidR[a]];
        pairC2[o] = c2; pairSV[o] = sv;
        ++o;
    }
}

// ---------------- final: block per output row, LDS accumulator, no global atomics ----------------
__global__ __launch_bounds__(256) void k_final_row(const int* __restrict__ rowptr,
                                                   const int* __restrict__ colptr,
                                                   const int* __restrict__ poff,
                                                   const int* __restrict__ pairC2, const float* __restrict__ pairSV,
                                                   const int* __restrict__ jv, const float* __restrict__ av,
                                                   float* __restrict__ out) {
    __shared__ __align__(16) float Orow[N_NODES];
    int r = blockIdx.x;
    int tid = threadIdx.x;
    float4* O4 = (float4*)Orow;
    float4 z = {0.f, 0.f, 0.f, 0.f};
#pragma unroll
    for (int t = 0; t < N_NODES / 4 / 256; ++t) O4[tid + t * 256] = z;
    __syncthreads();

    int pr0 = poff[rowptr[r]], pr1 = poff[rowptr[r + 1]];
    for (int p = pr0 + tid; p < pr1; p += 256) {
        int c2 = pairC2[p];
        float sv = pairSV[p];
        int b0 = colptr[c2], b1 = colptr[c2 + 1];
        for (int b = b0; b < b1; ++b) {
            atomicAdd(&Orow[jv[b]], sv * av[b]);
        }
    }
    __syncthreads();

    float4* o4 = (float4*)(out + (size_t)r * N_NODES);
#pragma unroll
    for (int t = 0; t < N_NODES / 4 / 256; ++t) o4[tid + t * 256] = O4[tid + t * 256];
}

extern "C" void kernel_launch(void* const* d_in, const int* in_sizes, int n_in,
                              void* d_out, int out_size, void* d_ws, size_t ws_size,
                              hipStream_t stream) {
    const float* x    = (const float*)d_in[0];
    const int* edges  = (const int*)d_in[1];
    const float* Wt   = (const float*)d_in[2];
    const float* Wp   = (const float*)d_in[3];
    const float* Wq   = (const float*)d_in[4];
    const float* Wk   = (const float*)d_in[5];
    float* out = (float*)d_out;

    char* w = (char*)d_ws;
    size_t off = 0;
    auto alloc = [&](size_t bytes) -> void* {
        void* p = w + off;
        off += (bytes + 255) & ~(size_t)255;
        return p;
    };
    float4* xp    = (float4*)alloc((size_t)N_NODES * 16);
    int*   knn    = (int*)  alloc((size_t)N_NODES * KNN * 4);
    float* qb     = (float*)alloc((size_t)N_NODES * H * 4);
    float* kb     = (float*)alloc((size_t)N_NODES * H * 4);
    float* att    = (float*)alloc((size_t)NE * 4);
    float* attn   = (float*)alloc((size_t)NE * 4);
    int*   degR   = (int*)  alloc((size_t)N_NODES * 4);
    int*   degC   = (int*)  alloc((size_t)N_NODES * 4);
    int*   rowptr = (int*)  alloc((size_t)(N_NODES + 4) * 4);
    int*   colptr = (int*)  alloc((size_t)(N_NODES + 4) * 4);
    int*   cursR  = (int*)  alloc((size_t)N_NODES * 4);
    int*   cursC  = (int*)  alloc((size_t)N_NODES * 4);
    int*   eidR   = (int*)  alloc((size_t)NE * 4);
    int*   eidC   = (int*)  alloc((size_t)NE * 4);
    int*   pcnt2  = (int*)  alloc((size_t)NE * 4);
    int*   poff   = (int*)  alloc((size_t)(NE + 1) * 4);
    int*   jv     = (int*)  alloc((size_t)NE * 4);
    float* av     = (float*)alloc((size_t)NE * 4);
    int*   pairC2 = (int*)  alloc((size_t)MAXPAIRS * 4);
    float* pairSV = (float*)alloc((size_t)MAXPAIRS * 4);

    k_init2<<<(N_NODES + 255) / 256, 256, 0, stream>>>(degR, degC, x, xp);
    k_hist<<<(NE + 255) / 256, 256, 0, stream>>>(edges, degR, degC);
    k_knn<<<N_NODES / 4, 256, 0, stream>>>(xp, knn);
    k_scan2<<<1, 128, 0, stream>>>(degR, degC, rowptr, colptr, cursR, cursC);
    k_scatter<<<(NE + 255) / 256, 256, 0, stream>>>(edges, rowptr, cursR, cursC, eidR, eidC, pcnt2);
    k_pscan<<<1, 1024, 0, stream>>>(pcnt2, poff);
    k_agg_feat_qk<<<N_NODES, 64, 0, stream>>>(xp, edges, rowptr, eidR, knn, Wt, Wp, Wq, Wk, qb, kb);
    k_att<<<(NE * 64) / 256, 256, 0, stream>>>(edges, qb, kb, att);
    k_softmax<<<(N_NODES + 255) / 256, 256, 0, stream>>>(rowptr, eidR, att, attn);
    k_fill<<<(NE + 255) / 256, 256, 0, stream>>>(edges, rowptr, eidR, eidC, poff, attn, jv, av, pairC2, pairSV);
    k_final_row<<<N_NODES, 256, 0, stream>>>(rowptr, colptr, poff, pairC2, pairSV, jv, av, out);
}

// Round 10
// 110.054 us; speedup vs baseline: 2.4052x; 1.1313x over previous
//
#include <hip/hip_runtime.h>
#include <math.h>

#define N_NODES 4096
#define H 64
#define NE 24576
#define KNN 15
#define KBUF 448
#define MAXP_ROW 512

__device__ __forceinline__ int mbcnt64(unsigned long long m) {
    int lo = __builtin_amdgcn_mbcnt_lo((unsigned int)m, 0u);
    return __builtin_amdgcn_mbcnt_hi((unsigned int)(m >> 32), lo);
}

// ---------------- init: deg counters + xp = (x,y,z,|x|^2) ----------------
__global__ __launch_bounds__(256) void k_init2(int* __restrict__ degR, int* __restrict__ degC,
                                               const float* __restrict__ x, float4* __restrict__ xp) {
    int tid = blockIdx.x * 256 + threadIdx.x;
    if (tid < N_NODES) {
        degR[tid] = 0; degC[tid] = 0;
        float a = x[tid * 3], b = x[tid * 3 + 1], c = x[tid * 3 + 2];
        xp[tid] = make_float4(a, b, c, a * a + b * b + c * c);
    }
}

// ---------------- histogram of original edges ----------------
__global__ void k_hist(const int* __restrict__ edges, int* degR, int* degC) {
    int e = blockIdx.x * blockDim.x + threadIdx.x;
    if (e < NE) {
        atomicAdd(&degR[edges[e]], 1);
        atomicAdd(&degC[edges[NE + e]], 1);
    }
}

// ---------------- barrier-free scan: wave0 -> rowptr/cursR, wave1 -> colptr/cursC ----------------
__global__ __launch_bounds__(128) void k_scan2(const int* __restrict__ degR, const int* __restrict__ degC,
                                               int* rowptr, int* colptr, int* cursR, int* cursC) {
    int w = threadIdx.x >> 6, lane = threadIdx.x & 63;
    const int* deg = w ? degC : degR;
    int* ptr  = w ? colptr : rowptr;
    int* curs = w ? cursC : cursR;
    const int4* d4 = (const int4*)deg + lane * 16;
    int4 v[16];
    int s = 0;
#pragma unroll
    for (int t = 0; t < 16; ++t) { v[t] = d4[t]; s += v[t].x + v[t].y + v[t].z + v[t].w; }
    int incl = s;
#pragma unroll
    for (int o = 1; o < 64; o <<= 1) { int u = __shfl_up(incl, o); if (lane >= o) incl += u; }
    int run = incl - s;
    int4* p4 = (int4*)ptr + lane * 16;
    int4* c4 = (int4*)curs + lane * 16;
#pragma unroll
    for (int t = 0; t < 16; ++t) {
        int4 o;
        o.x = run; run += v[t].x;
        o.y = run; run += v[t].y;
        o.z = run; run += v[t].z;
        o.w = run; run += v[t].w;
        p4[t] = o; c4[t] = o;
    }
    if (lane == 63) ptr[N_NODES] = run;
}

// ---------------- scatter: CSR-native arrays, no edge-id indirection downstream ----------------
__global__ void k_scatter(const int* __restrict__ edges, int* cursR, int* cursC,
                          int* __restrict__ colR, int* __restrict__ csrpos,
                          int* __restrict__ csr2csc, int* __restrict__ jv) {
    int e = blockIdx.x * blockDim.x + threadIdx.x;
    if (e < NE) {
        int r = edges[e], c = edges[NE + e];
        int p = atomicAdd(&cursR[r], 1);
        int q = atomicAdd(&cursC[c], 1);
        colR[p] = c;        // CSR column list
        csrpos[e] = p;      // edge -> CSR slot
        csr2csc[p] = q;     // CSR slot -> CSC slot
        jv[q] = r;          // CSC row list
    }
}

// ---------------- kNN: 1 wave = 1 block (max occupancy), u64 keys, bitonic selection ----------------
__global__ __launch_bounds__(64) void k_knn(const float4* __restrict__ xp, int* __restrict__ knn_idx) {
    __shared__ unsigned long long cb[KBUF];
    const int lane = threadIdx.x;
    const int i = blockIdx.x;
    const float4 pi = xp[i];
    unsigned long long tauKey;
    int cnt;

    auto sort64 = [&](unsigned long long key) -> unsigned long long {
#pragma unroll
        for (int k = 2; k <= 64; k <<= 1) {
#pragma unroll
            for (int j = 32; j > 0; j >>= 1) {
                if (j >= k) continue;
                unsigned long long other = __shfl_xor(key, j);
                bool asc = ((lane & k) == 0);
                bool takeMin = (((lane & j) == 0) == asc);
                bool less = key < other;
                key = (takeMin == less) ? key : other;
            }
        }
        return key;
    };

    auto tighten = [&]() {
        __builtin_amdgcn_wave_barrier();
        int n = (cnt + 63) >> 6;
        unsigned long long v[7];
        unsigned long long kmin = ~0ull;
#pragma unroll
        for (int t = 0; t < 7; ++t) {
            v[t] = ~0ull;
            if (t < n) {
                int s = t * 64 + lane;
                if (s < cnt) v[t] = cb[s];
                kmin = (v[t] < kmin) ? v[t] : kmin;
            }
        }
        unsigned long long T = __shfl(sort64(kmin), 14);
        __builtin_amdgcn_wave_barrier();
        int m = 0;
#pragma unroll
        for (int t = 0; t < 7; ++t) {
            if (t < n) {
                bool pred = (v[t] <= T);
                unsigned long long mk = __ballot(pred);
                if (pred) cb[m + mbcnt64(mk)] = v[t];
                m += __popcll(mk);
            }
        }
        cnt = m;
        tauKey = T;
        __builtin_amdgcn_wave_barrier();
    };

    // iter 0: store all 256 keys; tau from sorted lane-mins (upper bound on exact 15th)
    {
        unsigned long long kmin = ~0ull;
#pragma unroll
        for (int t = 0; t < 4; ++t) {
            int j = t * 64 + lane;
            float4 pj = xp[j];
            float d = pi.w + pj.w - 2.0f * (pi.x * pj.x + pi.y * pj.y + pi.z * pj.z);
            unsigned long long key = ((unsigned long long)__float_as_uint(d) << 32) | (unsigned)j;
            if (j == i) key = ~0ull;
            cb[j] = key;
            kmin = (key < kmin) ? key : kmin;
        }
        cnt = 256;
        tauKey = __shfl(sort64(kmin), 14);
        __builtin_amdgcn_wave_barrier();
    }

    for (int iter = 1; iter < 16; ++iter) {
        const int jb = iter * 256;
        float4 p0 = xp[jb + lane];
        float4 p1 = xp[jb + 64 + lane];
        float4 p2 = xp[jb + 128 + lane];
        float4 p3 = xp[jb + 192 + lane];
        float d0 = pi.w + p0.w - 2.0f * (pi.x * p0.x + pi.y * p0.y + pi.z * p0.z);
        float d1 = pi.w + p1.w - 2.0f * (pi.x * p1.x + pi.y * p1.y + pi.z * p1.z);
        float d2 = pi.w + p2.w - 2.0f * (pi.x * p2.x + pi.y * p2.y + pi.z * p2.z);
        float d3 = pi.w + p3.w - 2.0f * (pi.x * p3.x + pi.y * p3.y + pi.z * p3.z);
#pragma unroll
        for (int t = 0; t < 4; ++t) {
            float d = (t == 0) ? d0 : (t == 1) ? d1 : (t == 2) ? d2 : d3;
            int j = jb + t * 64 + lane;
            unsigned long long key = ((unsigned long long)__float_as_uint(d) << 32) | (unsigned)j;
            bool pred = (key < tauKey) && (j != i);
            unsigned long long m = __ballot(pred);
            if (m) {
                if (pred) cb[cnt + mbcnt64(m)] = key;
                cnt += __popcll(m);
            }
        }
        if (cnt > KBUF - 256) tighten();
    }

    tighten();
    if (cnt > 64) tighten();
    unsigned long long fin = (lane < cnt) ? cb[lane] : ~0ull;
    fin = sort64(fin);
    if (lane < KNN) knn_idx[i * KNN + lane] = (int)(fin & 0xffffffffu);
}

// ---------------- DevConv max-agg + Wp/Wq/Wk (fused, block = 1 wave per node) ----------------
__global__ __launch_bounds__(64) void k_agg_feat_qk(const float4* __restrict__ xp,
                                                    const int* __restrict__ rowptr, const int* __restrict__ colR,
                                                    const int* __restrict__ knn_idx, const float* __restrict__ Wt,
                                                    const float* __restrict__ Wp, const float* __restrict__ Wq,
                                                    const float* __restrict__ Wk,
                                                    float* __restrict__ qb, float* __restrict__ kb) {
    int i = blockIdx.x, h = threadIdx.x;
    __shared__ float mrow[H], frow[H];
    float w0 = Wt[h * 3], w1 = Wt[h * 3 + 1], w2 = Wt[h * 3 + 2];
    float4 pi = xp[i];
    float m = -INFINITY;
    int s0 = rowptr[i], s1 = rowptr[i + 1];
    for (int s = s0; s < s1; ++s) {
        float4 pj = xp[colR[s]];
        m = fmaxf(m, w0 * (pj.x - pi.x) + w1 * (pj.y - pi.y) + w2 * (pj.z - pi.z));
    }
    for (int t = 0; t < KNN; ++t) {
        float4 pj = xp[knn_idx[i * KNN + t]];
        m = fmaxf(m, w0 * (pj.x - pi.x) + w1 * (pj.y - pi.y) + w2 * (pj.z - pi.z));
    }
    if (!(m > -INFINITY)) m = 0.0f;
    mrow[h] = m;
    __syncthreads();
    float f = 0.f;
    for (int k2 = 0; k2 < H; ++k2) f += Wp[h * H + k2] * mrow[k2];
    frow[h] = f;
    __syncthreads();
    float qv = 0.f, kv = 0.f;
    for (int k2 = 0; k2 < H; ++k2) {
        float fr = frow[k2];
        qv += Wq[h * H + k2] * fr;
        kv += Wk[h * H + k2] * fr;
    }
    qb[i * H + h] = qv;
    kb[i * H + h] = kv;
}

// ---------------- attention scores: 1 wave per edge, written CSR-ordered ----------------
__global__ __launch_bounds__(256) void k_att(const int* __restrict__ edges, const int* __restrict__ csrpos,
                                             const float* __restrict__ qb, const float* __restrict__ kb,
                                             float* __restrict__ attR) {
    int wid = (blockIdx.x * blockDim.x + threadIdx.x) >> 6;
    int lane = threadIdx.x & 63;
    if (wid >= NE) return;
    int r = edges[wid], c = edges[NE + wid];
    float v = qb[r * H + lane] * kb[c * H + lane];
#pragma unroll
    for (int o = 32; o > 0; o >>= 1) v += __shfl_xor(v, o);
    if (lane == 0) attR[csrpos[wid]] = v;
}

// ---------------- segment softmax: thread per node, contiguous CSR reads; emits attnR + av ----------------
__global__ void k_softmax(const int* __restrict__ rowptr, const int* __restrict__ csr2csc,
                          const float* __restrict__ attR, float* __restrict__ attnR, float* __restrict__ av) {
    int i = blockIdx.x * blockDim.x + threadIdx.x;
    if (i >= N_NODES) return;
    int s0 = rowptr[i], s1 = rowptr[i + 1];
    float m = -INFINITY;
    for (int s = s0; s < s1; ++s) m = fmaxf(m, attR[s]);
    float den = 0.f;
    for (int s = s0; s < s1; ++s) den += expf(attR[s] - m);
    for (int s = s0; s < s1; ++s) {
        float a = expf(attR[s] - m) / den;
        attnR[s] = a;
        av[csr2csc[s]] = a;
    }
}

// ---------------- final: block per output row; in-LDS pair build; LDS accumulate; dense store ----------------
__global__ __launch_bounds__(256) void k_final_row(const int* __restrict__ rowptr,
                                                   const int* __restrict__ colptr,
                                                   const int* __restrict__ colR, const float* __restrict__ attnR,
                                                   const int* __restrict__ jv, const float* __restrict__ av,
                                                   float* __restrict__ out) {
    __shared__ __align__(16) float Orow[N_NODES];
    __shared__ int   pc2[MAXP_ROW];
    __shared__ float psv[MAXP_ROW];
    __shared__ int npair;
    int r = blockIdx.x;
    int tid = threadIdx.x;
    float4* O4 = (float4*)Orow;
    float4 z = {0.f, 0.f, 0.f, 0.f};
#pragma unroll
    for (int t = 0; t < N_NODES / 4 / 256; ++t) O4[tid + t * 256] = z;

    // wave 0 builds the pair list (T-row expansion) in LDS
    if (tid < 64) {
        int lane = tid;
        int base = 0;
        int s0 = rowptr[r], s1 = rowptr[r + 1];
        for (int s = s0; s < s1; ++s) {
            int c = colR[s];          // uniform across wave -> broadcast
            float sv = attnR[s];
            int a0 = rowptr[c], d = rowptr[c + 1] - a0;
            for (int a = lane; a < d; a += 64) {
                pc2[base + a] = colR[a0 + a];
                psv[base + a] = sv;
            }
            base += d;
        }
        if (lane == 0) npair = base;
    }
    __syncthreads();

    int np = npair;
    for (int p = tid; p < np; p += 256) {
        int c2 = pc2[p];
        float sv = psv[p];
        int b0 = colptr[c2], b1 = colptr[c2 + 1];
        for (int b = b0; b < b1; ++b) {
            atomicAdd(&Orow[jv[b]], sv * av[b]);
        }
    }
    __syncthreads();

    float4* o4 = (float4*)(out + (size_t)r * N_NODES);
#pragma unroll
    for (int t = 0; t < N_NODES / 4 / 256; ++t) o4[tid + t * 256] = O4[tid + t * 256];
}

extern "C" void kernel_launch(void* const* d_in, const int* in_sizes, int n_in,
                              void* d_out, int out_size, void* d_ws, size_t ws_size,
                              hipStream_t stream) {
    const float* x    = (const float*)d_in[0];
    const int* edges  = (const int*)d_in[1];
    const float* Wt   = (const float*)d_in[2];
    const float* Wp   = (const float*)d_in[3];
    const float* Wq   = (const float*)d_in[4];
    const float* Wk   = (const float*)d_in[5];
    float* out = (float*)d_out;

    char* w = (char*)d_ws;
    size_t off = 0;
    auto alloc = [&](size_t bytes) -> void* {
        void* p = w + off;
        off += (bytes + 255) & ~(size_t)255;
        return p;
    };
    float4* xp     = (float4*)alloc((size_t)N_NODES * 16);
    int*   knn     = (int*)  alloc((size_t)N_NODES * KNN * 4);
    float* qb      = (float*)alloc((size_t)N_NODES * H * 4);
    float* kb      = (float*)alloc((size_t)N_NODES * H * 4);
    int*   degR    = (int*)  alloc((size_t)N_NODES * 4);
    int*   degC    = (int*)  alloc((size_t)N_NODES * 4);
    int*   rowptr  = (int*)  alloc((size_t)(N_NODES + 4) * 4);
    int*   colptr  = (int*)  alloc((size_t)(N_NODES + 4) * 4);
    int*   cursR   = (int*)  alloc((size_t)N_NODES * 4);
    int*   cursC   = (int*)  alloc((size_t)N_NODES * 4);
    int*   colR    = (int*)  alloc((size_t)NE * 4);
    int*   csrpos  = (int*)  alloc((size_t)NE * 4);
    int*   csr2csc = (int*)  alloc((size_t)NE * 4);
    int*   jv      = (int*)  alloc((size_t)NE * 4);
    float* attR    = (float*)alloc((size_t)NE * 4);
    float* attnR   = (float*)alloc((size_t)NE * 4);
    float* av      = (float*)alloc((size_t)NE * 4);

    k_init2<<<(N_NODES + 255) / 256, 256, 0, stream>>>(degR, degC, x, xp);
    k_hist<<<(NE + 255) / 256, 256, 0, stream>>>(edges, degR, degC);
    k_knn<<<N_NODES, 64, 0, stream>>>(xp, knn);
    k_scan2<<<1, 128, 0, stream>>>(degR, degC, rowptr, colptr, cursR, cursC);
    k_scatter<<<(NE + 255) / 256, 256, 0, stream>>>(edges, cursR, cursC, colR, csrpos, csr2csc, jv);
    k_agg_feat_qk<<<N_NODES, 64, 0, stream>>>(xp, rowptr, colR, knn, Wt, Wp, Wq, Wk, qb, kb);
    k_att<<<(NE * 64) / 256, 256, 0, stream>>>(edges, csrpos, qb, kb, attR);
    k_softmax<<<(N_NODES + 255) / 256, 256, 0, stream>>>(rowptr, csr2csc, attR, attnR, av);
    k_final_row<<<N_NODES, 256, 0, stream>>>(rowptr, colptr, colR, attnR, jv, av, out);
}

// Round 11
// 100.793 us; speedup vs baseline: 2.6263x; 1.0919x over previous
//
#include <hip/hip_runtime.h>
#include <math.h>

#define N_NODES 4096
#define H 64
#define NE 24576
#define KNN 15
#define KBUF 448
#define MAXP_ROW 512

__device__ __forceinline__ int mbcnt64(unsigned long long m) {
    int lo = __builtin_amdgcn_mbcnt_lo((unsigned int)m, 0u);
    return __builtin_amdgcn_mbcnt_hi((unsigned int)(m >> 32), lo);
}

// ---------------- init: deg counters + xp = (x,y,z,|x|^2) ----------------
__global__ __launch_bounds__(256) void k_init2(int* __restrict__ degR, int* __restrict__ degC,
                                               const float* __restrict__ x, float4* __restrict__ xp) {
    int tid = blockIdx.x * 256 + threadIdx.x;
    if (tid < N_NODES) {
        degR[tid] = 0; degC[tid] = 0;
        float a = x[tid * 3], b = x[tid * 3 + 1], c = x[tid * 3 + 2];
        xp[tid] = make_float4(a, b, c, a * a + b * b + c * c);
    }
}

// ---------------- barrier-free scan: wave0 -> rowptr/cursR, wave1 -> colptr/cursC ----------------
__global__ __launch_bounds__(128) void k_scan2(const int* __restrict__ degR, const int* __restrict__ degC,
                                               int* rowptr, int* colptr, int* cursR, int* cursC) {
    int w = threadIdx.x >> 6, lane = threadIdx.x & 63;
    const int* deg = w ? degC : degR;
    int* ptr  = w ? colptr : rowptr;
    int* curs = w ? cursC : cursR;
    const int4* d4 = (const int4*)deg + lane * 16;
    int4 v[16];
    int s = 0;
#pragma unroll
    for (int t = 0; t < 16; ++t) { v[t] = d4[t]; s += v[t].x + v[t].y + v[t].z + v[t].w; }
    int incl = s;
#pragma unroll
    for (int o = 1; o < 64; o <<= 1) { int u = __shfl_up(incl, o); if (lane >= o) incl += u; }
    int run = incl - s;
    int4* p4 = (int4*)ptr + lane * 16;
    int4* c4 = (int4*)curs + lane * 16;
#pragma unroll
    for (int t = 0; t < 16; ++t) {
        int4 o;
        o.x = run; run += v[t].x;
        o.y = run; run += v[t].y;
        o.z = run; run += v[t].z;
        o.w = run; run += v[t].w;
        p4[t] = o; c4[t] = o;
    }
    if (lane == 63) ptr[N_NODES] = run;
}

// ---------------- scatter: CSR-native arrays; jav.x = CSC row bits ----------------
__global__ void k_scatter(const int* __restrict__ edges, int* cursR, int* cursC,
                          int* __restrict__ colR, int* __restrict__ csr2csc, float2* __restrict__ jav) {
    int e = blockIdx.x * blockDim.x + threadIdx.x;
    if (e < NE) {
        int r = edges[e], c = edges[NE + e];
        int p = atomicAdd(&cursR[r], 1);
        int q = atomicAdd(&cursC[c], 1);
        colR[p] = c;                       // CSR column list
        csr2csc[p] = q;                    // CSR slot -> CSC slot
        ((int*)jav)[2 * q] = r;            // CSC row list (int bits in .x)
    }
}

// ---------------- kNN (1 wave = 1 block) + histogram piggyback on blocks 0..383 ----------------
__global__ __launch_bounds__(64) void k_knn(const float4* __restrict__ xp, int* __restrict__ knn_idx,
                                            const int* __restrict__ edges, int* __restrict__ degR,
                                            int* __restrict__ degC) {
    __shared__ unsigned long long cb[KBUF];
    const int lane = threadIdx.x;
    const int i = blockIdx.x;

    // histogram piggyback: runs after k_init2 (stream-serialized), before k_scan2
    if (i < NE / 64) {
        int e = i * 64 + lane;
        atomicAdd(&degR[edges[e]], 1);
        atomicAdd(&degC[edges[NE + e]], 1);
    }

    const float4 pi = xp[i];
    unsigned long long tauKey;
    int cnt;

    auto sort64 = [&](unsigned long long key) -> unsigned long long {
#pragma unroll
        for (int k = 2; k <= 64; k <<= 1) {
#pragma unroll
            for (int j = 32; j > 0; j >>= 1) {
                if (j >= k) continue;
                unsigned long long other = __shfl_xor(key, j);
                bool asc = ((lane & k) == 0);
                bool takeMin = (((lane & j) == 0) == asc);
                bool less = key < other;
                key = (takeMin == less) ? key : other;
            }
        }
        return key;
    };

    auto tighten = [&]() {
        __builtin_amdgcn_wave_barrier();
        int n = (cnt + 63) >> 6;
        unsigned long long v[7];
        unsigned long long kmin = ~0ull;
#pragma unroll
        for (int t = 0; t < 7; ++t) {
            v[t] = ~0ull;
            if (t < n) {
                int s = t * 64 + lane;
                if (s < cnt) v[t] = cb[s];
                kmin = (v[t] < kmin) ? v[t] : kmin;
            }
        }
        unsigned long long T = __shfl(sort64(kmin), 14);
        __builtin_amdgcn_wave_barrier();
        int m = 0;
#pragma unroll
        for (int t = 0; t < 7; ++t) {
            if (t < n) {
                bool pred = (v[t] <= T);
                unsigned long long mk = __ballot(pred);
                if (pred) cb[m + mbcnt64(mk)] = v[t];
                m += __popcll(mk);
            }
        }
        cnt = m;
        tauKey = T;
        __builtin_amdgcn_wave_barrier();
    };

    // iter 0: store all 256 keys; tau from sorted lane-mins (upper bound on exact 15th)
    {
        unsigned long long kmin = ~0ull;
#pragma unroll
        for (int t = 0; t < 4; ++t) {
            int j = t * 64 + lane;
            float4 pj = xp[j];
            float d = pi.w + pj.w - 2.0f * (pi.x * pj.x + pi.y * pj.y + pi.z * pj.z);
            unsigned long long key = ((unsigned long long)__float_as_uint(d) << 32) | (unsigned)j;
            if (j == i) key = ~0ull;
            cb[j] = key;
            kmin = (key < kmin) ? key : kmin;
        }
        cnt = 256;
        tauKey = __shfl(sort64(kmin), 14);
        __builtin_amdgcn_wave_barrier();
    }

    for (int iter = 1; iter < 16; ++iter) {
        const int jb = iter * 256;
        float4 p0 = xp[jb + lane];
        float4 p1 = xp[jb + 64 + lane];
        float4 p2 = xp[jb + 128 + lane];
        float4 p3 = xp[jb + 192 + lane];
        float d0 = pi.w + p0.w - 2.0f * (pi.x * p0.x + pi.y * p0.y + pi.z * p0.z);
        float d1 = pi.w + p1.w - 2.0f * (pi.x * p1.x + pi.y * p1.y + pi.z * p1.z);
        float d2 = pi.w + p2.w - 2.0f * (pi.x * p2.x + pi.y * p2.y + pi.z * p2.z);
        float d3 = pi.w + p3.w - 2.0f * (pi.x * p3.x + pi.y * p3.y + pi.z * p3.z);
#pragma unroll
        for (int t = 0; t < 4; ++t) {
            float d = (t == 0) ? d0 : (t == 1) ? d1 : (t == 2) ? d2 : d3;
            int j = jb + t * 64 + lane;
            unsigned long long key = ((unsigned long long)__float_as_uint(d) << 32) | (unsigned)j;
            bool pred = (key < tauKey) && (j != i);
            unsigned long long m = __ballot(pred);
            if (m) {
                if (pred) cb[cnt + mbcnt64(m)] = key;
                cnt += __popcll(m);
            }
        }
        if (cnt > KBUF - 256) tighten();
    }

    tighten();
    if (cnt > 64) tighten();
    unsigned long long fin = (lane < cnt) ? cb[lane] : ~0ull;
    fin = sort64(fin);
    if (lane < KNN) knn_idx[i * KNN + lane] = (int)(fin & 0xffffffffu);
}

// ---------------- DevConv max-agg + Wp/Wq/Wk (fused, block = 1 wave per node) ----------------
__global__ __launch_bounds__(64) void k_agg_feat_qk(const float4* __restrict__ xp,
                                                    const int* __restrict__ rowptr, const int* __restrict__ colR,
                                                    const int* __restrict__ knn_idx, const float* __restrict__ Wt,
                                                    const float* __restrict__ Wp, const float* __restrict__ Wq,
                                                    const float* __restrict__ Wk,
                                                    float* __restrict__ qb, float* __restrict__ kb) {
    int i = blockIdx.x, h = threadIdx.x;
    __shared__ float mrow[H], frow[H];
    float w0 = Wt[h * 3], w1 = Wt[h * 3 + 1], w2 = Wt[h * 3 + 2];
    float4 pi = xp[i];
    float m = -INFINITY;
    int s0 = rowptr[i], s1 = rowptr[i + 1];
    for (int s = s0; s < s1; ++s) {
        float4 pj = xp[colR[s]];
        m = fmaxf(m, w0 * (pj.x - pi.x) + w1 * (pj.y - pi.y) + w2 * (pj.z - pi.z));
    }
    for (int t = 0; t < KNN; ++t) {
        float4 pj = xp[knn_idx[i * KNN + t]];
        m = fmaxf(m, w0 * (pj.x - pi.x) + w1 * (pj.y - pi.y) + w2 * (pj.z - pi.z));
    }
    if (!(m > -INFINITY)) m = 0.0f;
    mrow[h] = m;
    __syncthreads();
    float f = 0.f;
    for (int k2 = 0; k2 < H; ++k2) f += Wp[h * H + k2] * mrow[k2];
    frow[h] = f;
    __syncthreads();
    float qv = 0.f, kv = 0.f;
    for (int k2 = 0; k2 < H; ++k2) {
        float fr = frow[k2];
        qv += Wq[h * H + k2] * fr;
        kv += Wk[h * H + k2] * fr;
    }
    qb[i * H + h] = qv;
    kb[i * H + h] = kv;
}

// ---------------- fused attention + segment softmax: 1 wave per node ----------------
__global__ __launch_bounds__(64) void k_attsm(const int* __restrict__ rowptr, const int* __restrict__ colR,
                                              const int* __restrict__ csr2csc,
                                              const float* __restrict__ qb, const float* __restrict__ kb,
                                              float* __restrict__ attnR, float2* __restrict__ jav) {
    __shared__ float sc[64];
    int i = blockIdx.x, lane = threadIdx.x;
    int s0 = rowptr[i];
    int deg = rowptr[i + 1] - s0;
    if (deg == 0) return;
    float qv = qb[i * H + lane];
    float m = -INFINITY;
    for (int s = 0; s < deg; ++s) {
        int c = colR[s0 + s];                 // wave-uniform broadcast
        float v = qv * kb[c * H + lane];      // coalesced
#pragma unroll
        for (int o = 32; o > 0; o >>= 1) v += __shfl_xor(v, o);
        if (lane == 0) sc[s] = v;
        m = fmaxf(m, v);                      // wave-uniform
    }
    __builtin_amdgcn_wave_barrier();
    float den = 0.f;
    for (int s = 0; s < deg; ++s) den += expf(sc[s] - m);
    if (lane < deg) {
        float a = expf(sc[lane] - m) / den;
        attnR[s0 + lane] = a;
        ((float*)jav)[2 * csr2csc[s0 + lane] + 1] = a;   // av into jav.y
    }
}

// ---------------- final: block per output row; wave0 builds pairs while waves1-3 zero LDS ----------------
__global__ __launch_bounds__(256) void k_final_row(const int* __restrict__ rowptr,
                                                   const int* __restrict__ colptr,
                                                   const int* __restrict__ colR, const float* __restrict__ attnR,
                                                   const float2* __restrict__ jav,
                                                   float* __restrict__ out) {
    __shared__ __align__(16) float Orow[N_NODES];
    __shared__ int   pc2[MAXP_ROW];
    __shared__ float psv[MAXP_ROW];
    __shared__ int npair;
    int r = blockIdx.x;
    int tid = threadIdx.x;
    float4* O4 = (float4*)Orow;
    float4 z = {0.f, 0.f, 0.f, 0.f};

    if (tid >= 64) {
        // waves 1-3: zero the accumulator row
        for (int t = tid - 64; t < N_NODES / 4; t += 192) O4[t] = z;
    } else {
        // wave 0: build the pair list (T-row expansion) in LDS
        int lane = tid;
        int base = 0;
        int s0 = rowptr[r], s1 = rowptr[r + 1];
        for (int s = s0; s < s1; ++s) {
            int c = colR[s];                  // uniform -> broadcast
            float sv = attnR[s];
            int a0 = rowptr[c], d = rowptr[c + 1] - a0;
            for (int a = lane; a < d; a += 64) {
                pc2[base + a] = colR[a0 + a];
                psv[base + a] = sv;
            }
            base += d;
        }
        if (lane == 0) npair = base;
    }
    __syncthreads();

    int np = npair;
    for (int p = tid; p < np; p += 256) {
        int c2 = pc2[p];
        float sv = psv[p];
        int b0 = colptr[c2], b1 = colptr[c2 + 1];
        for (int b = b0; b < b1; ++b) {
            float2 v = jav[b];
            atomicAdd(&Orow[__float_as_int(v.x)], sv * v.y);
        }
    }
    __syncthreads();

    float4* o4 = (float4*)(out + (size_t)r * N_NODES);
#pragma unroll
    for (int t = 0; t < N_NODES / 4 / 256; ++t) o4[tid + t * 256] = O4[tid + t * 256];
}

extern "C" void kernel_launch(void* const* d_in, const int* in_sizes, int n_in,
                              void* d_out, int out_size, void* d_ws, size_t ws_size,
                              hipStream_t stream) {
    const float* x    = (const float*)d_in[0];
    const int* edges  = (const int*)d_in[1];
    const float* Wt   = (const float*)d_in[2];
    const float* Wp   = (const float*)d_in[3];
    const float* Wq   = (const float*)d_in[4];
    const float* Wk   = (const float*)d_in[5];
    float* out = (float*)d_out;

    char* w = (char*)d_ws;
    size_t off = 0;
    auto alloc = [&](size_t bytes) -> void* {
        void* p = w + off;
        off += (bytes + 255) & ~(size_t)255;
        return p;
    };
    float4* xp      = (float4*)alloc((size_t)N_NODES * 16);
    int*   knn      = (int*)  alloc((size_t)N_NODES * KNN * 4);
    float* qb       = (float*)alloc((size_t)N_NODES * H * 4);
    float* kb       = (float*)alloc((size_t)N_NODES * H * 4);
    int*   degR     = (int*)  alloc((size_t)N_NODES * 4);
    int*   degC     = (int*)  alloc((size_t)N_NODES * 4);
    int*   rowptr   = (int*)  alloc((size_t)(N_NODES + 4) * 4);
    int*   colptr   = (int*)  alloc((size_t)(N_NODES + 4) * 4);
    int*   cursR    = (int*)  alloc((size_t)N_NODES * 4);
    int*   cursC    = (int*)  alloc((size_t)N_NODES * 4);
    int*   colR     = (int*)  alloc((size_t)NE * 4);
    int*   csr2csc  = (int*)  alloc((size_t)NE * 4);
    float* attnR    = (float*)alloc((size_t)NE * 4);
    float2* jav     = (float2*)alloc((size_t)NE * 8);

    k_init2<<<(N_NODES + 255) / 256, 256, 0, stream>>>(degR, degC, x, xp);
    k_knn<<<N_NODES, 64, 0, stream>>>(xp, knn, edges, degR, degC);
    k_scan2<<<1, 128, 0, stream>>>(degR, degC, rowptr, colptr, cursR, cursC);
    k_scatter<<<(NE + 255) / 256, 256, 0, stream>>>(edges, cursR, cursC, colR, csr2csc, jav);
    k_agg_feat_qk<<<N_NODES, 64, 0, stream>>>(xp, rowptr, colR, knn, Wt, Wp, Wq, Wk, qb, kb);
    k_attsm<<<N_NODES, 64, 0, stream>>>(rowptr, colR, csr2csc, qb, kb, attnR, jav);
    k_final_row<<<N_NODES, 256, 0, stream>>>(rowptr, colptr, colR, attnR, jav, out);
}